// Round 9
// baseline (1676.546 us; speedup 1.0000x reference)
//
#include <hip/hip_runtime.h>
#include <hip/hip_bf16.h>
#include <math.h>
#include <stdint.h>

// N = 32768 nodes, D = 256 features, E = 524288 edges, L = 3 layers,
// K = 16384 (top-k), C = 11 classes.

// ---------------------------------------------------------------------------
// 1. concat f0,f1 -> x0 [N][256]
// ---------------------------------------------------------------------------
__global__ __launch_bounds__(256) void concat_kernel(const float* __restrict__ f0,
                                                     const float* __restrict__ f1,
                                                     float* __restrict__ x,
                                                     int N) {
    int gid = blockIdx.x * blockDim.x + threadIdx.x;  // one float4 per thread
    int total = N * 64;                               // 64 float4 per row
    if (gid >= total) return;
    int n = gid >> 6;
    int q = gid & 63;
    float4 v;
    if (q < 32) v = *(const float4*)(f0 + (size_t)n * 128 + q * 4);
    else        v = *(const float4*)(f1 + (size_t)n * 128 + (q - 32) * 4);
    *(float4*)(x + (size_t)n * 256 + q * 4) = v;
}

// ---------------------------------------------------------------------------
// 2a. histogram of dst
// ---------------------------------------------------------------------------
__global__ __launch_bounds__(256) void count_kernel(const int* __restrict__ dst,
                                                    int* __restrict__ counts, int E) {
    int e = blockIdx.x * blockDim.x + threadIdx.x;
    if (e < E) atomicAdd(&counts[dst[e]], 1);
}

// ---------------------------------------------------------------------------
// 2b. exclusive scan of counts -> offsets[N+1]; zero counts (reused as cursor)
// ---------------------------------------------------------------------------
__global__ __launch_bounds__(1024) void scan_kernel(int* __restrict__ counts,
                                                    int* __restrict__ offs,
                                                    int N, int E) {
    __shared__ int s[1024];
    int t = threadIdx.x;
    int base = t * 32;
    int local[32];
    int sum = 0;
    #pragma unroll
    for (int j = 0; j < 32; ++j) { local[j] = counts[base + j]; sum += local[j]; }
    s[t] = sum;
    __syncthreads();
    for (int off = 1; off < 1024; off <<= 1) {
        int other = (t >= off) ? s[t - off] : 0;
        __syncthreads();
        s[t] += other;
        __syncthreads();
    }
    int run = s[t] - sum;  // exclusive base for this thread
    #pragma unroll
    for (int j = 0; j < 32; ++j) {
        offs[base + j] = run;
        run += local[j];
        counts[base + j] = 0;   // reset: reused as cursor in fill_kernel
    }
    if (t == 1023) offs[N] = E;
}

// ---------------------------------------------------------------------------
// 2c. scatter edge ids into CSR buckets
// ---------------------------------------------------------------------------
__global__ __launch_bounds__(256) void fill_kernel(const int* __restrict__ dst,
                                                   const int* __restrict__ offs,
                                                   int* __restrict__ cursor,
                                                   int* __restrict__ csr, int E) {
    int e = blockIdx.x * blockDim.x + threadIdx.x;
    if (e >= E) return;
    int d = dst[e];
    int pos = offs[d] + atomicAdd(&cursor[d], 1);
    csr[pos] = e;
}

// ---------------------------------------------------------------------------
// 2d. per-bucket insertion sort by edge id (deterministic), map edge->src
// ---------------------------------------------------------------------------
__global__ __launch_bounds__(256) void bsort_kernel(int* __restrict__ csr,
                                                    const int* __restrict__ offs,
                                                    const int* __restrict__ src,
                                                    int N) {
    int i = blockIdx.x * blockDim.x + threadIdx.x;
    if (i >= N) return;
    int beg = offs[i], end = offs[i + 1];
    for (int a = beg + 1; a < end; ++a) {
        int v = csr[a];
        int b = a - 1;
        while (b >= beg && csr[b] > v) { csr[b + 1] = csr[b]; --b; }
        csr[b + 1] = v;
    }
    for (int p = beg; p < end; ++p) csr[p] = src[csr[p]];
}

// ---------------------------------------------------------------------------
// 3. segment sum: agg[n][:] = sum over csr bucket of x[src][:]
// ---------------------------------------------------------------------------
__global__ __launch_bounds__(256) void segsum_kernel(const float* __restrict__ X,
                                                     const int* __restrict__ csr,
                                                     const int* __restrict__ offs,
                                                     float* __restrict__ AGG, int N) {
    int w = threadIdx.x >> 6;
    int lane = threadIdx.x & 63;
    int n = blockIdx.x * 4 + w;
    if (n >= N) return;
    int beg = offs[n], end = offs[n + 1];
    float4 acc = make_float4(0.f, 0.f, 0.f, 0.f);
    for (int p = beg; p < end; ++p) {
        int s = csr[p];
        float4 v = *(const float4*)(X + (size_t)s * 256 + lane * 4);
        acc.x += v.x; acc.y += v.y; acc.z += v.z; acc.w += v.w;
    }
    *(float4*)(AGG + (size_t)n * 256 + lane * 4) = acc;
}

// ---------------------------------------------------------------------------
// 4. fused GEMM: Y = relu(X @ W1 + G @ W2 + bias)   [N,512-split] x [512,256]
//    128x128 tile, BK=32, 256 threads, 4x(4x4) quadrant micro-tile,
//    register staging + LDS DOUBLE BUFFER -> ONE barrier per K-step:
//      { issue loads(kt+1) ; compute buf[kt&1] ; store buf[(kt+1)&1] ; bar }
//    Store target was last read at kt-1 (already barrier-separated) -> safe.
//    LDS 2x33.8KB = 67.6KB: 2 blocks/CU, which grid (512 blocks) caps anyway.
//    NOTE: no min-waves arg in __launch_bounds__ (round-5 spill lesson);
//    16x8 microtile regressed (round-7: VGPR 200, occupancy 11%) - keep 4x4x4.
// ---------------------------------------------------------------------------
#define GBM 128
#define GBN 128
#define GBK 32

#define GEMM_LOAD_STAGE(kt)                                                          \
    {                                                                                \
        const int kb = (kt) * GBK;                                                   \
        const float* Asrc = (kb < 256) ? X : G;                                      \
        const float* Wsrc = (kb < 256) ? W1 : W2;                                    \
        const int kloc = kb & 255;                                                   \
        a_st0 = *(const float4*)(Asrc + (size_t)(rowBase + ar) * 256 + kloc + ak);   \
        a_st1 = *(const float4*)(Asrc + (size_t)(rowBase + ar + 64) * 256 + kloc + ak); \
        a_st2 = *(const float4*)(Asrc + (size_t)(rowBase + ar) * 256 + kloc + 16 + ak); \
        a_st3 = *(const float4*)(Asrc + (size_t)(rowBase + ar + 64) * 256 + kloc + 16 + ak); \
        w_st0 = *(const float4*)(Wsrc + (size_t)(kloc + wk) * 256 + colBase + wc);   \
        w_st1 = *(const float4*)(Wsrc + (size_t)(kloc + wk + 8) * 256 + colBase + wc); \
        w_st2 = *(const float4*)(Wsrc + (size_t)(kloc + wk + 16) * 256 + colBase + wc); \
        w_st3 = *(const float4*)(Wsrc + (size_t)(kloc + wk + 24) * 256 + colBase + wc); \
    }

#define GEMM_STORE_STAGE(buf)                                                        \
    {                                                                                \
        float (*Asb)[GBM + 4] = As[buf];                                             \
        float (*Wsb)[GBN + 4] = Ws[buf];                                             \
        _Pragma("unroll")                                                            \
        for (int j = 0; j < 4; ++j) {                                                \
            Asb[ak + j][ar]           = ((const float*)&a_st0)[j];                   \
            Asb[ak + j][ar + 64]      = ((const float*)&a_st1)[j];                   \
            Asb[16 + ak + j][ar]      = ((const float*)&a_st2)[j];                   \
            Asb[16 + ak + j][ar + 64] = ((const float*)&a_st3)[j];                   \
        }                                                                            \
        *(float4*)&Wsb[wk][wc]      = w_st0;                                         \
        *(float4*)&Wsb[wk + 8][wc]  = w_st1;                                         \
        *(float4*)&Wsb[wk + 16][wc] = w_st2;                                         \
        *(float4*)&Wsb[wk + 24][wc] = w_st3;                                         \
    }

__global__ __launch_bounds__(256) void gemm_two_kernel(const float* __restrict__ X,
                                                       const float* __restrict__ G,
                                                       const float* __restrict__ W1,
                                                       const float* __restrict__ W2,
                                                       const float* __restrict__ bias,
                                                       float* __restrict__ Y) {
    __shared__ float As[2][GBK][GBM + 4];
    __shared__ float Ws[2][GBK][GBN + 4];
    const int tid = threadIdx.x;
    const int tcol = tid & 15;
    const int trow = tid >> 4;
    const int rowBase = blockIdx.y * GBM;
    const int colBase = blockIdx.x * GBN;

    const int ar = tid >> 2;
    const int ak = (tid & 3) * 4;
    const int wk = tid >> 5;
    const int wc = (tid & 31) * 4;

    float4 a_st0, a_st1, a_st2, a_st3, w_st0, w_st1, w_st2, w_st3;

    float acc[4][4][4];
    #pragma unroll
    for (int q = 0; q < 4; ++q)
        #pragma unroll
        for (int i = 0; i < 4; ++i)
            #pragma unroll
            for (int j = 0; j < 4; ++j) acc[q][i][j] = 0.f;

    GEMM_LOAD_STAGE(0);
    GEMM_STORE_STAGE(0);
    __syncthreads();

    const int NT = 512 / GBK;
    for (int kt = 0; kt < NT; ++kt) {
        const int cur = kt & 1;
        if (kt + 1 < NT) GEMM_LOAD_STAGE(kt + 1);   // loads fly under compute
        {
            const float (*Asr)[GBM + 4] = As[cur];
            const float (*Wsr)[GBN + 4] = Ws[cur];
            #pragma unroll
            for (int kk = 0; kk < GBK; ++kk) {
                float a0[4], a1[4], w0[4], w1[4];
                *(float4*)a0 = *(const float4*)&Asr[kk][trow * 4];
                *(float4*)a1 = *(const float4*)&Asr[kk][64 + trow * 4];
                *(float4*)w0 = *(const float4*)&Wsr[kk][tcol * 4];
                *(float4*)w1 = *(const float4*)&Wsr[kk][64 + tcol * 4];
                #pragma unroll
                for (int i = 0; i < 4; ++i)
                    #pragma unroll
                    for (int j = 0; j < 4; ++j) {
                        acc[0][i][j] = fmaf(a0[i], w0[j], acc[0][i][j]);
                        acc[1][i][j] = fmaf(a0[i], w1[j], acc[1][i][j]);
                        acc[2][i][j] = fmaf(a1[i], w0[j], acc[2][i][j]);
                        acc[3][i][j] = fmaf(a1[i], w1[j], acc[3][i][j]);
                    }
            }
        }
        if (kt + 1 < NT) GEMM_STORE_STAGE((kt + 1) & 1);  // other buffer: safe
        __syncthreads();
    }

    #pragma unroll
    for (int h = 0; h < 2; ++h) {
        #pragma unroll
        for (int i = 0; i < 4; ++i) {
            const int row = rowBase + h * 64 + trow * 4 + i;
            #pragma unroll
            for (int g = 0; g < 2; ++g) {
                const int colb = colBase + g * 64 + tcol * 4;
                float o[4];
                #pragma unroll
                for (int j = 0; j < 4; ++j)
                    o[j] = fmaxf(acc[h * 2 + g][i][j] + bias[colb + j], 0.f);
                *(float4*)(Y + (size_t)row * 256 + colb) = *(const float4*)&o[0];
            }
        }
    }
}

// ---------------------------------------------------------------------------
// 5a. per-node dots: yr[n] = x3[n].Wpr, yn[n] = x3[n].Wpn   (f64)
// ---------------------------------------------------------------------------
__global__ __launch_bounds__(256) void dot_kernel(const float* __restrict__ X3,
                                                  const float* __restrict__ Wpr,
                                                  const float* __restrict__ Wpn,
                                                  double* __restrict__ yr,
                                                  double* __restrict__ yn, int N) {
    int w = threadIdx.x >> 6;
    int lane = threadIdx.x & 63;
    int n = blockIdx.x * 4 + w;
    if (n >= N) return;
    float4 xv = *(const float4*)(X3 + (size_t)n * 256 + lane * 4);
    float4 wr = *(const float4*)(Wpr + lane * 4);
    float4 wn = *(const float4*)(Wpn + lane * 4);
    double dr = (double)xv.x * wr.x + (double)xv.y * wr.y +
                (double)xv.z * wr.z + (double)xv.w * wr.w;
    double dn = (double)xv.x * wn.x + (double)xv.y * wn.y +
                (double)xv.z * wn.z + (double)xv.w * wn.w;
    #pragma unroll
    for (int o = 32; o > 0; o >>= 1) {
        dr += __shfl_down(dr, o, 64);
        dn += __shfl_down(dn, o, 64);
    }
    if (lane == 0) { yr[n] = dr; yn[n] = dn; }
}

// ---------------------------------------------------------------------------
// 5b. score[n] = yr[n] + sum_{bucket} yn[src] + bp; emit order-preserving key
// ---------------------------------------------------------------------------
__global__ __launch_bounds__(256) void score_gather_kernel(
        const double* __restrict__ yr, const double* __restrict__ yn,
        const int* __restrict__ csr, const int* __restrict__ offs,
        const float* __restrict__ bp,
        double* __restrict__ sc, unsigned long long* __restrict__ keys, int N) {
    int n = blockIdx.x * blockDim.x + threadIdx.x;
    if (n >= N) return;
    double s = yr[n] + (double)bp[0];
    int beg = offs[n], end = offs[n + 1];
    for (int p = beg; p < end; ++p) s += yn[csr[p]];
    sc[n] = s;
    long long sb = __double_as_longlong(s);
    keys[n] = (sb < 0) ? ~(unsigned long long)sb
                       : ((unsigned long long)sb | 0x8000000000000000ULL);
}

// ---------------------------------------------------------------------------
// 6a. tiled exact rank-count on uint64 keys.
//     RTI=1024 i (4 regs/thread) x RTJ=512 j (LDS) -> 2048 blocks (8/CU).
// ---------------------------------------------------------------------------
#define RTI 1024
#define RTJ 512
__global__ __launch_bounds__(256) void rank_count_kernel(
        const unsigned long long* __restrict__ keys,
        int* __restrict__ rankcnt, int N) {
    __shared__ __align__(16) unsigned long long sk[RTJ];
    const int tid = threadIdx.x;
    const int ibase = blockIdx.y * RTI;
    const int jbase = blockIdx.x * RTJ;

    unsigned long long ki[4];
    #pragma unroll
    for (int r = 0; r < 4; ++r) ki[r] = keys[ibase + r * 256 + tid];
    for (int t = tid; t < RTJ; t += 256) sk[t] = keys[jbase + t];
    __syncthreads();

    int cnt[4] = {0, 0, 0, 0};
    if (jbase + RTJ <= ibase) {
        for (int u = 0; u < RTJ; u += 8) {
            ulonglong2 p0 = *(const ulonglong2*)&sk[u];
            ulonglong2 p1 = *(const ulonglong2*)&sk[u + 2];
            ulonglong2 p2 = *(const ulonglong2*)&sk[u + 4];
            ulonglong2 p3 = *(const ulonglong2*)&sk[u + 6];
            #pragma unroll
            for (int r = 0; r < 4; ++r) {
                cnt[r] += (int)(p0.x >= ki[r]) + (int)(p0.y >= ki[r])
                        + (int)(p1.x >= ki[r]) + (int)(p1.y >= ki[r])
                        + (int)(p2.x >= ki[r]) + (int)(p2.y >= ki[r])
                        + (int)(p3.x >= ki[r]) + (int)(p3.y >= ki[r]);
            }
        }
    } else if (jbase >= ibase + RTI) {
        for (int u = 0; u < RTJ; u += 8) {
            ulonglong2 p0 = *(const ulonglong2*)&sk[u];
            ulonglong2 p1 = *(const ulonglong2*)&sk[u + 2];
            ulonglong2 p2 = *(const ulonglong2*)&sk[u + 4];
            ulonglong2 p3 = *(const ulonglong2*)&sk[u + 6];
            #pragma unroll
            for (int r = 0; r < 4; ++r) {
                cnt[r] += (int)(p0.x > ki[r]) + (int)(p0.y > ki[r])
                        + (int)(p1.x > ki[r]) + (int)(p1.y > ki[r])
                        + (int)(p2.x > ki[r]) + (int)(p2.y > ki[r])
                        + (int)(p3.x > ki[r]) + (int)(p3.y > ki[r]);
            }
        }
    } else {
        int thr[4];
        #pragma unroll
        for (int r = 0; r < 4; ++r) thr[r] = ibase + r * 256 + tid - jbase;
        for (int u = 0; u < RTJ; ++u) {
            unsigned long long kj = sk[u];
            #pragma unroll
            for (int r = 0; r < 4; ++r)
                cnt[r] += (kj > ki[r]) || (kj == ki[r] && u < thr[r]);
        }
    }
    #pragma unroll
    for (int r = 0; r < 4; ++r)
        atomicAdd(&rankcnt[ibase + r * 256 + tid], cnt[r]);
}

// ---------------------------------------------------------------------------
// 6b. scatter by rank
// ---------------------------------------------------------------------------
__global__ __launch_bounds__(256) void rank_scatter_kernel(
        const int* __restrict__ rankcnt,
        const double* __restrict__ sc,
        int* __restrict__ perm,
        double* __restrict__ topd, int N, int K) {
    int i = blockIdx.x * blockDim.x + threadIdx.x;
    if (i >= N) return;
    int rank = rankcnt[i];
    if (rank < K) { perm[rank] = i; topd[rank] = sc[i]; }
}

// ---------------------------------------------------------------------------
// 7. head: out[r] = relu(x3[perm[r]] * tanh(score_r)) @ Wc + bc  (f64 accum)
// ---------------------------------------------------------------------------
__global__ __launch_bounds__(256) void out_kernel(const float* __restrict__ X3,
                                                  const int* __restrict__ perm,
                                                  const double* __restrict__ topd,
                                                  const float* __restrict__ Wc,
                                                  const float* __restrict__ bc,
                                                  float* __restrict__ out, int K) {
    int w = threadIdx.x >> 6;
    int lane = threadIdx.x & 63;
    int r = blockIdx.x * 4 + w;
    if (r >= K) return;
    int p = perm[r];
    double t = tanh(topd[r]);
    float4 xv = *(const float4*)(X3 + (size_t)p * 256 + lane * 4);
    double xp[4];
    xp[0] = (double)xv.x * t; xp[1] = (double)xv.y * t;
    xp[2] = (double)xv.z * t; xp[3] = (double)xv.w * t;
    #pragma unroll
    for (int j = 0; j < 4; ++j) xp[j] = xp[j] > 0.0 ? xp[j] : 0.0;
    double acc[11];
    #pragma unroll
    for (int c = 0; c < 11; ++c) acc[c] = 0.0;
    #pragma unroll
    for (int j = 0; j < 4; ++j) {
        const float* wrow = Wc + (size_t)(lane * 4 + j) * 11;
        #pragma unroll
        for (int c = 0; c < 11; ++c) acc[c] += xp[j] * (double)wrow[c];
    }
    #pragma unroll
    for (int c = 0; c < 11; ++c) {
        double v = acc[c];
        #pragma unroll
        for (int o = 32; o > 0; o >>= 1) v += __shfl_down(v, o, 64);
        if (lane == 0) out[(size_t)r * 11 + c] = (float)(v + (double)bc[c]);
    }
}

// ---------------------------------------------------------------------------
// launch
// ---------------------------------------------------------------------------
extern "C" void kernel_launch(void* const* d_in, const int* in_sizes, int n_in,
                              void* d_out, int out_size, void* d_ws, size_t ws_size,
                              hipStream_t stream) {
    const float* f0  = (const float*)d_in[0];
    const float* f1  = (const float*)d_in[1];
    const int*   ei  = (const int*)d_in[2];
    const float* Wr  = (const float*)d_in[3];
    const float* Wn  = (const float*)d_in[4];
    const float* b   = (const float*)d_in[5];
    const float* Wpr = (const float*)d_in[6];
    const float* Wpn = (const float*)d_in[7];
    const float* bp  = (const float*)d_in[8];
    const float* Wc  = (const float*)d_in[9];
    const float* bc  = (const float*)d_in[10];
    float* out = (float*)d_out;

    const int N = in_sizes[0] / 128;   // 32768
    const int E = in_sizes[2] / 2;     // 524288
    const int K = (N + 1) / 2;         // 16384
    const int L = in_sizes[5] / 256;   // 3 layers

    const int* src = ei;
    const int* dst = ei + E;

    // workspace layout (256B aligned slices)
    char* p = (char*)d_ws;
    auto take = [&](size_t bytes) {
        char* r = p;
        p += (bytes + 255) & ~(size_t)255;
        return r;
    };
    float*  xA      = (float*)take((size_t)N * 256 * 4);
    float*  xB      = (float*)take((size_t)N * 256 * 4);
    float*  agg     = (float*)take((size_t)N * 256 * 4);
    int*    counts  = (int*)take((size_t)N * 4);
    int*    offs    = (int*)take((size_t)(N + 1) * 4);
    int*    csr     = (int*)take((size_t)E * 4);
    double* sc      = (double*)take((size_t)N * 8);
    unsigned long long* keys = (unsigned long long*)take((size_t)N * 8);
    int*    rankcnt = (int*)take((size_t)N * 4);
    double* topd    = (double*)take((size_t)K * 8);
    int*    perm    = (int*)take((size_t)K * 4);
    double* yrv     = (double*)take((size_t)N * 8);
    double* ynv     = (double*)take((size_t)N * 8);
    (void)ws_size;

    hipMemsetAsync(counts, 0, (size_t)N * 4, stream);
    hipMemsetAsync(rankcnt, 0, (size_t)N * 4, stream);

    concat_kernel<<<(N * 64 + 255) / 256, 256, 0, stream>>>(f0, f1, xA, N);
    count_kernel<<<(E + 255) / 256, 256, 0, stream>>>(dst, counts, E);
    scan_kernel<<<1, 1024, 0, stream>>>(counts, offs, N, E);
    fill_kernel<<<(E + 255) / 256, 256, 0, stream>>>(dst, offs, counts, csr, E);
    bsort_kernel<<<(N + 255) / 256, 256, 0, stream>>>(csr, offs, src, N);

    float* xcur = xA;
    float* xnext = xB;
    for (int i = 0; i < L; ++i) {
        segsum_kernel<<<N / 4, 256, 0, stream>>>(xcur, csr, offs, agg, N);
        gemm_two_kernel<<<dim3(256 / GBN, N / GBM), 256, 0, stream>>>(
            xcur, agg, Wr + (size_t)i * 65536, Wn + (size_t)i * 65536,
            b + (size_t)i * 256, xnext);
        float* tmp = xcur; xcur = xnext; xnext = tmp;
    }
    // xcur == x3
    dot_kernel<<<N / 4, 256, 0, stream>>>(xcur, Wpr, Wpn, yrv, ynv, N);
    score_gather_kernel<<<N / 256, 256, 0, stream>>>(yrv, ynv, csr, offs, bp, sc, keys, N);
    rank_count_kernel<<<dim3(N / RTJ, N / RTI), 256, 0, stream>>>(keys, rankcnt, N);
    rank_scatter_kernel<<<(N + 255) / 256, 256, 0, stream>>>(rankcnt, sc, perm, topd, N, K);
    out_kernel<<<K / 4, 256, 0, stream>>>(xcur, perm, topd, Wc, bc, out, K);
}

// Round 10
// 806.762 us; speedup vs baseline: 2.0781x; 2.0781x over previous
//
#include <hip/hip_runtime.h>
#include <hip/hip_bf16.h>
#include <math.h>
#include <stdint.h>

// N = 32768 nodes, D = 256 features, E = 524288 edges, L = 3 layers,
// K = 16384 (top-k), C = 11 classes.
// GEMM history: 4x(4x4) fused @124 VGPR = 126us/layer (best).
//   - __launch_bounds__(256,4) clamp -> spill (r5, 1.2GB/dispatch)
//   - 16x8 microtile -> 200 VGPR, 11% occ, 169us (r7)
//   - LDS double-buffer -> 256 VGPR, spill, 420us+ (r8)
// Conclusion: keep single-buffer 2-barrier schedule; VGPR headroom is the
// binding constraint, not barrier count.

// ---------------------------------------------------------------------------
// 2a. histogram of dst
// ---------------------------------------------------------------------------
__global__ __launch_bounds__(256) void count_kernel(const int* __restrict__ dst,
                                                    int* __restrict__ counts, int E) {
    int e = blockIdx.x * blockDim.x + threadIdx.x;
    if (e < E) atomicAdd(&counts[dst[e]], 1);
}

// ---------------------------------------------------------------------------
// 2b. exclusive scan of counts -> offsets[N+1]; zero counts (reused as cursor)
// ---------------------------------------------------------------------------
__global__ __launch_bounds__(1024) void scan_kernel(int* __restrict__ counts,
                                                    int* __restrict__ offs,
                                                    int N, int E) {
    __shared__ int s[1024];
    int t = threadIdx.x;
    int base = t * 32;
    int local[32];
    int sum = 0;
    #pragma unroll
    for (int j = 0; j < 32; ++j) { local[j] = counts[base + j]; sum += local[j]; }
    s[t] = sum;
    __syncthreads();
    for (int off = 1; off < 1024; off <<= 1) {
        int other = (t >= off) ? s[t - off] : 0;
        __syncthreads();
        s[t] += other;
        __syncthreads();
    }
    int run = s[t] - sum;  // exclusive base for this thread
    #pragma unroll
    for (int j = 0; j < 32; ++j) {
        offs[base + j] = run;
        run += local[j];
        counts[base + j] = 0;   // reset: reused as cursor in fill_kernel
    }
    if (t == 1023) offs[N] = E;
}

// ---------------------------------------------------------------------------
// 2c. scatter edge ids into CSR buckets
// ---------------------------------------------------------------------------
__global__ __launch_bounds__(256) void fill_kernel(const int* __restrict__ dst,
                                                   const int* __restrict__ offs,
                                                   int* __restrict__ cursor,
                                                   int* __restrict__ csr, int E) {
    int e = blockIdx.x * blockDim.x + threadIdx.x;
    if (e >= E) return;
    int d = dst[e];
    int pos = offs[d] + atomicAdd(&cursor[d], 1);
    csr[pos] = e;
}

// ---------------------------------------------------------------------------
// 2d. per-bucket insertion sort by edge id (deterministic), map edge->src
// ---------------------------------------------------------------------------
__global__ __launch_bounds__(256) void bsort_kernel(int* __restrict__ csr,
                                                    const int* __restrict__ offs,
                                                    const int* __restrict__ src,
                                                    int N) {
    int i = blockIdx.x * blockDim.x + threadIdx.x;
    if (i >= N) return;
    int beg = offs[i], end = offs[i + 1];
    for (int a = beg + 1; a < end; ++a) {
        int v = csr[a];
        int b = a - 1;
        while (b >= beg && csr[b] > v) { csr[b + 1] = csr[b]; --b; }
        csr[b + 1] = v;
    }
    for (int p = beg; p < end; ++p) csr[p] = src[csr[p]];
}

// ---------------------------------------------------------------------------
// 3. segment sum: agg[n][:] = sum over csr bucket of x[src][:]
// ---------------------------------------------------------------------------
__global__ __launch_bounds__(256) void segsum_kernel(const float* __restrict__ X,
                                                     const int* __restrict__ csr,
                                                     const int* __restrict__ offs,
                                                     float* __restrict__ AGG, int N) {
    int w = threadIdx.x >> 6;
    int lane = threadIdx.x & 63;
    int n = blockIdx.x * 4 + w;
    if (n >= N) return;
    int beg = offs[n], end = offs[n + 1];
    float4 acc = make_float4(0.f, 0.f, 0.f, 0.f);
    for (int p = beg; p < end; ++p) {
        int s = csr[p];
        float4 v = *(const float4*)(X + (size_t)s * 256 + lane * 4);
        acc.x += v.x; acc.y += v.y; acc.z += v.z; acc.w += v.w;
    }
    *(float4*)(AGG + (size_t)n * 256 + lane * 4) = acc;
}

// ---------------------------------------------------------------------------
// 3f. first-layer segment sum: x0 = [f0|f1] virtual concat (col<128 -> f0).
//     Per lane the float4 lies wholly in f0 or f1 -> one base select.
// ---------------------------------------------------------------------------
__global__ __launch_bounds__(256) void segsum_first_kernel(
        const float* __restrict__ f0, const float* __restrict__ f1,
        const int* __restrict__ csr, const int* __restrict__ offs,
        float* __restrict__ AGG, int N) {
    int w = threadIdx.x >> 6;
    int lane = threadIdx.x & 63;
    int n = blockIdx.x * 4 + w;
    if (n >= N) return;
    const float* base = (lane < 32) ? (f0 + lane * 4) : (f1 + (lane - 32) * 4);
    int beg = offs[n], end = offs[n + 1];
    float4 acc = make_float4(0.f, 0.f, 0.f, 0.f);
    for (int p = beg; p < end; ++p) {
        int s = csr[p];
        float4 v = *(const float4*)(base + (size_t)s * 128);
        acc.x += v.x; acc.y += v.y; acc.z += v.z; acc.w += v.w;
    }
    *(float4*)(AGG + (size_t)n * 256 + lane * 4) = acc;
}

// ---------------------------------------------------------------------------
// 4. fused GEMM: Y = relu(X @ W1 + G @ W2 + bias)   [N,512-split] x [512,256]
//    128x128 tile, BK=32, 256 threads, 4x(4x4) quadrant micro-tile,
//    register single-stage staging (round-4 config, 124 VGPR).
// ---------------------------------------------------------------------------
#define GBM 128
#define GBN 128
#define GBK 32

__device__ __forceinline__ float4 ldA01(const float* __restrict__ f0,
                                        const float* __restrict__ f1,
                                        int row, int c) {
    // virtual concat row: col c<128 from f0, else f1 (c is float4-aligned)
    return (c < 128) ? *(const float4*)(f0 + (size_t)row * 128 + c)
                     : *(const float4*)(f1 + (size_t)row * 128 + (c - 128));
}

#define GEMM_W_LOAD(Wsrc, kloc)                                                      \
    {                                                                                \
        w_st0 = *(const float4*)((Wsrc) + (size_t)((kloc) + wk) * 256 + colBase + wc);     \
        w_st1 = *(const float4*)((Wsrc) + (size_t)((kloc) + wk + 8) * 256 + colBase + wc); \
        w_st2 = *(const float4*)((Wsrc) + (size_t)((kloc) + wk + 16) * 256 + colBase + wc);\
        w_st3 = *(const float4*)((Wsrc) + (size_t)((kloc) + wk + 24) * 256 + colBase + wc);\
    }

#define GEMM_LOAD_STAGE(kt)                                                          \
    {                                                                                \
        const int kb = (kt) * GBK;                                                   \
        const float* Asrc = (kb < 256) ? X : G;                                      \
        const float* Wsrc = (kb < 256) ? W1 : W2;                                    \
        const int kloc = kb & 255;                                                   \
        a_st0 = *(const float4*)(Asrc + (size_t)(rowBase + ar) * 256 + kloc + ak);   \
        a_st1 = *(const float4*)(Asrc + (size_t)(rowBase + ar + 64) * 256 + kloc + ak); \
        a_st2 = *(const float4*)(Asrc + (size_t)(rowBase + ar) * 256 + kloc + 16 + ak); \
        a_st3 = *(const float4*)(Asrc + (size_t)(rowBase + ar + 64) * 256 + kloc + 16 + ak); \
        GEMM_W_LOAD(Wsrc, kloc)                                                      \
    }

#define GEMM_LOAD_STAGE_F(kt)                                                        \
    {                                                                                \
        const int kb = (kt) * GBK;                                                   \
        if (kb < 256) {                                                              \
            a_st0 = ldA01(f0, f1, rowBase + ar,      kb + ak);                       \
            a_st1 = ldA01(f0, f1, rowBase + ar + 64, kb + ak);                       \
            a_st2 = ldA01(f0, f1, rowBase + ar,      kb + 16 + ak);                  \
            a_st3 = ldA01(f0, f1, rowBase + ar + 64, kb + 16 + ak);                  \
            GEMM_W_LOAD(W1, kb)                                                      \
        } else {                                                                     \
            const int kloc = kb & 255;                                               \
            a_st0 = *(const float4*)(G + (size_t)(rowBase + ar) * 256 + kloc + ak);  \
            a_st1 = *(const float4*)(G + (size_t)(rowBase + ar + 64) * 256 + kloc + ak); \
            a_st2 = *(const float4*)(G + (size_t)(rowBase + ar) * 256 + kloc + 16 + ak); \
            a_st3 = *(const float4*)(G + (size_t)(rowBase + ar + 64) * 256 + kloc + 16 + ak); \
            GEMM_W_LOAD(W2, kloc)                                                    \
        }                                                                            \
    }

#define GEMM_STORE_STAGE()                                                           \
    {                                                                                \
        _Pragma("unroll")                                                            \
        for (int j = 0; j < 4; ++j) {                                                \
            As[ak + j][ar]           = ((const float*)&a_st0)[j];                    \
            As[ak + j][ar + 64]      = ((const float*)&a_st1)[j];                    \
            As[16 + ak + j][ar]      = ((const float*)&a_st2)[j];                    \
            As[16 + ak + j][ar + 64] = ((const float*)&a_st3)[j];                    \
        }                                                                            \
        *(float4*)&Ws[wk][wc]      = w_st0;                                          \
        *(float4*)&Ws[wk + 8][wc]  = w_st1;                                          \
        *(float4*)&Ws[wk + 16][wc] = w_st2;                                          \
        *(float4*)&Ws[wk + 24][wc] = w_st3;                                          \
    }

#define GEMM_COMPUTE()                                                               \
    {                                                                                \
        _Pragma("unroll")                                                            \
        for (int kk = 0; kk < GBK; ++kk) {                                           \
            float a0[4], a1[4], w0[4], w1[4];                                        \
            *(float4*)a0 = *(const float4*)&As[kk][trow * 4];                        \
            *(float4*)a1 = *(const float4*)&As[kk][64 + trow * 4];                   \
            *(float4*)w0 = *(const float4*)&Ws[kk][tcol * 4];                        \
            *(float4*)w1 = *(const float4*)&Ws[kk][64 + tcol * 4];                   \
            _Pragma("unroll")                                                        \
            for (int i = 0; i < 4; ++i)                                              \
                _Pragma("unroll")                                                    \
                for (int j = 0; j < 4; ++j) {                                        \
                    acc[0][i][j] = fmaf(a0[i], w0[j], acc[0][i][j]);                 \
                    acc[1][i][j] = fmaf(a0[i], w1[j], acc[1][i][j]);                 \
                    acc[2][i][j] = fmaf(a1[i], w0[j], acc[2][i][j]);                 \
                    acc[3][i][j] = fmaf(a1[i], w1[j], acc[3][i][j]);                 \
                }                                                                    \
        }                                                                            \
    }

#define GEMM_EPILOGUE()                                                              \
    {                                                                                \
        _Pragma("unroll")                                                            \
        for (int h = 0; h < 2; ++h) {                                                \
            _Pragma("unroll")                                                        \
            for (int i = 0; i < 4; ++i) {                                            \
                const int row = rowBase + h * 64 + trow * 4 + i;                     \
                _Pragma("unroll")                                                    \
                for (int g = 0; g < 2; ++g) {                                        \
                    const int colb = colBase + g * 64 + tcol * 4;                    \
                    float o[4];                                                      \
                    _Pragma("unroll")                                                \
                    for (int j = 0; j < 4; ++j)                                      \
                        o[j] = fmaxf(acc[h * 2 + g][i][j] + bias[colb + j], 0.f);    \
                    *(float4*)(Y + (size_t)row * 256 + colb) = *(const float4*)&o[0];\
                }                                                                    \
            }                                                                        \
        }                                                                            \
    }

#define GEMM_PREAMBLE()                                                              \
    __shared__ float As[GBK][GBM + 4];                                               \
    __shared__ float Ws[GBK][GBN + 4];                                               \
    const int tid = threadIdx.x;                                                     \
    const int tcol = tid & 15;                                                       \
    const int trow = tid >> 4;                                                       \
    const int rowBase = blockIdx.y * GBM;                                            \
    const int colBase = blockIdx.x * GBN;                                            \
    const int ar = tid >> 2;                                                         \
    const int ak = (tid & 3) * 4;                                                    \
    const int wk = tid >> 5;                                                         \
    const int wc = (tid & 31) * 4;                                                   \
    float4 a_st0, a_st1, a_st2, a_st3, w_st0, w_st1, w_st2, w_st3;                   \
    float acc[4][4][4];                                                              \
    _Pragma("unroll")                                                                \
    for (int q = 0; q < 4; ++q)                                                      \
        _Pragma("unroll")                                                            \
        for (int i = 0; i < 4; ++i)                                                  \
            _Pragma("unroll")                                                        \
            for (int j = 0; j < 4; ++j) acc[q][i][j] = 0.f;

__global__ __launch_bounds__(256) void gemm_two_kernel(const float* __restrict__ X,
                                                       const float* __restrict__ G,
                                                       const float* __restrict__ W1,
                                                       const float* __restrict__ W2,
                                                       const float* __restrict__ bias,
                                                       float* __restrict__ Y) {
    GEMM_PREAMBLE();
    GEMM_LOAD_STAGE(0);
    for (int kt = 0; kt < 512 / GBK; ++kt) {
        __syncthreads();   // previous tile fully consumed
        GEMM_STORE_STAGE();
        __syncthreads();
        if (kt < 512 / GBK - 1) GEMM_LOAD_STAGE(kt + 1);  // overlap with compute
        GEMM_COMPUTE();
    }
    GEMM_EPILOGUE();
}

// first layer: X = virtual concat of f0|f1 (concat kernel eliminated)
__global__ __launch_bounds__(256) void gemm_first_kernel(const float* __restrict__ f0,
                                                         const float* __restrict__ f1,
                                                         const float* __restrict__ G,
                                                         const float* __restrict__ W1,
                                                         const float* __restrict__ W2,
                                                         const float* __restrict__ bias,
                                                         float* __restrict__ Y) {
    GEMM_PREAMBLE();
    GEMM_LOAD_STAGE_F(0);
    for (int kt = 0; kt < 512 / GBK; ++kt) {
        __syncthreads();
        GEMM_STORE_STAGE();
        __syncthreads();
        if (kt < 512 / GBK - 1) GEMM_LOAD_STAGE_F(kt + 1);
        GEMM_COMPUTE();
    }
    GEMM_EPILOGUE();
}

// ---------------------------------------------------------------------------
// 5a. per-node dots: yr[n] = x3[n].Wpr, yn[n] = x3[n].Wpn   (f64)
// ---------------------------------------------------------------------------
__global__ __launch_bounds__(256) void dot_kernel(const float* __restrict__ X3,
                                                  const float* __restrict__ Wpr,
                                                  const float* __restrict__ Wpn,
                                                  double* __restrict__ yr,
                                                  double* __restrict__ yn, int N) {
    int w = threadIdx.x >> 6;
    int lane = threadIdx.x & 63;
    int n = blockIdx.x * 4 + w;
    if (n >= N) return;
    float4 xv = *(const float4*)(X3 + (size_t)n * 256 + lane * 4);
    float4 wr = *(const float4*)(Wpr + lane * 4);
    float4 wn = *(const float4*)(Wpn + lane * 4);
    double dr = (double)xv.x * wr.x + (double)xv.y * wr.y +
                (double)xv.z * wr.z + (double)xv.w * wr.w;
    double dn = (double)xv.x * wn.x + (double)xv.y * wn.y +
                (double)xv.z * wn.z + (double)xv.w * wn.w;
    #pragma unroll
    for (int o = 32; o > 0; o >>= 1) {
        dr += __shfl_down(dr, o, 64);
        dn += __shfl_down(dn, o, 64);
    }
    if (lane == 0) { yr[n] = dr; yn[n] = dn; }
}

// ---------------------------------------------------------------------------
// 5b. score[n] = yr[n] + sum_{bucket} yn[src] + bp; emit order-preserving key
// ---------------------------------------------------------------------------
__global__ __launch_bounds__(256) void score_gather_kernel(
        const double* __restrict__ yr, const double* __restrict__ yn,
        const int* __restrict__ csr, const int* __restrict__ offs,
        const float* __restrict__ bp,
        double* __restrict__ sc, unsigned long long* __restrict__ keys, int N) {
    int n = blockIdx.x * blockDim.x + threadIdx.x;
    if (n >= N) return;
    double s = yr[n] + (double)bp[0];
    int beg = offs[n], end = offs[n + 1];
    for (int p = beg; p < end; ++p) s += yn[csr[p]];
    sc[n] = s;
    long long sb = __double_as_longlong(s);
    keys[n] = (sb < 0) ? ~(unsigned long long)sb
                       : ((unsigned long long)sb | 0x8000000000000000ULL);
}

// ---------------------------------------------------------------------------
// 6a. tiled exact rank-count on uint64 keys.
//     RTI=1024 i (4 regs/thread) x RTJ=512 j (LDS) -> 2048 blocks (8/CU).
// ---------------------------------------------------------------------------
#define RTI 1024
#define RTJ 512
__global__ __launch_bounds__(256) void rank_count_kernel(
        const unsigned long long* __restrict__ keys,
        int* __restrict__ rankcnt, int N) {
    __shared__ __align__(16) unsigned long long sk[RTJ];
    const int tid = threadIdx.x;
    const int ibase = blockIdx.y * RTI;
    const int jbase = blockIdx.x * RTJ;

    unsigned long long ki[4];
    #pragma unroll
    for (int r = 0; r < 4; ++r) ki[r] = keys[ibase + r * 256 + tid];
    for (int t = tid; t < RTJ; t += 256) sk[t] = keys[jbase + t];
    __syncthreads();

    int cnt[4] = {0, 0, 0, 0};
    if (jbase + RTJ <= ibase) {
        for (int u = 0; u < RTJ; u += 8) {
            ulonglong2 p0 = *(const ulonglong2*)&sk[u];
            ulonglong2 p1 = *(const ulonglong2*)&sk[u + 2];
            ulonglong2 p2 = *(const ulonglong2*)&sk[u + 4];
            ulonglong2 p3 = *(const ulonglong2*)&sk[u + 6];
            #pragma unroll
            for (int r = 0; r < 4; ++r) {
                cnt[r] += (int)(p0.x >= ki[r]) + (int)(p0.y >= ki[r])
                        + (int)(p1.x >= ki[r]) + (int)(p1.y >= ki[r])
                        + (int)(p2.x >= ki[r]) + (int)(p2.y >= ki[r])
                        + (int)(p3.x >= ki[r]) + (int)(p3.y >= ki[r]);
            }
        }
    } else if (jbase >= ibase + RTI) {
        for (int u = 0; u < RTJ; u += 8) {
            ulonglong2 p0 = *(const ulonglong2*)&sk[u];
            ulonglong2 p1 = *(const ulonglong2*)&sk[u + 2];
            ulonglong2 p2 = *(const ulonglong2*)&sk[u + 4];
            ulonglong2 p3 = *(const ulonglong2*)&sk[u + 6];
            #pragma unroll
            for (int r = 0; r < 4; ++r) {
                cnt[r] += (int)(p0.x > ki[r]) + (int)(p0.y > ki[r])
                        + (int)(p1.x > ki[r]) + (int)(p1.y > ki[r])
                        + (int)(p2.x > ki[r]) + (int)(p2.y > ki[r])
                        + (int)(p3.x > ki[r]) + (int)(p3.y > ki[r]);
            }
        }
    } else {
        int thr[4];
        #pragma unroll
        for (int r = 0; r < 4; ++r) thr[r] = ibase + r * 256 + tid - jbase;
        for (int u = 0; u < RTJ; ++u) {
            unsigned long long kj = sk[u];
            #pragma unroll
            for (int r = 0; r < 4; ++r)
                cnt[r] += (kj > ki[r]) || (kj == ki[r] && u < thr[r]);
        }
    }
    #pragma unroll
    for (int r = 0; r < 4; ++r)
        atomicAdd(&rankcnt[ibase + r * 256 + tid], cnt[r]);
}

// ---------------------------------------------------------------------------
// 6b. scatter by rank
// ---------------------------------------------------------------------------
__global__ __launch_bounds__(256) void rank_scatter_kernel(
        const int* __restrict__ rankcnt,
        const double* __restrict__ sc,
        int* __restrict__ perm,
        double* __restrict__ topd, int N, int K) {
    int i = blockIdx.x * blockDim.x + threadIdx.x;
    if (i >= N) return;
    int rank = rankcnt[i];
    if (rank < K) { perm[rank] = i; topd[rank] = sc[i]; }
}

// ---------------------------------------------------------------------------
// 7. head: out[r] = relu(x3[perm[r]] * tanh(score_r)) @ Wc + bc  (f64 accum)
// ---------------------------------------------------------------------------
__global__ __launch_bounds__(256) void out_kernel(const float* __restrict__ X3,
                                                  const int* __restrict__ perm,
                                                  const double* __restrict__ topd,
                                                  const float* __restrict__ Wc,
                                                  const float* __restrict__ bc,
                                                  float* __restrict__ out, int K) {
    int w = threadIdx.x >> 6;
    int lane = threadIdx.x & 63;
    int r = blockIdx.x * 4 + w;
    if (r >= K) return;
    int p = perm[r];
    double t = tanh(topd[r]);
    float4 xv = *(const float4*)(X3 + (size_t)p * 256 + lane * 4);
    double xp[4];
    xp[0] = (double)xv.x * t; xp[1] = (double)xv.y * t;
    xp[2] = (double)xv.z * t; xp[3] = (double)xv.w * t;
    #pragma unroll
    for (int j = 0; j < 4; ++j) xp[j] = xp[j] > 0.0 ? xp[j] : 0.0;
    double acc[11];
    #pragma unroll
    for (int c = 0; c < 11; ++c) acc[c] = 0.0;
    #pragma unroll
    for (int j = 0; j < 4; ++j) {
        const float* wrow = Wc + (size_t)(lane * 4 + j) * 11;
        #pragma unroll
        for (int c = 0; c < 11; ++c) acc[c] += xp[j] * (double)wrow[c];
    }
    #pragma unroll
    for (int c = 0; c < 11; ++c) {
        double v = acc[c];
        #pragma unroll
        for (int o = 32; o > 0; o >>= 1) v += __shfl_down(v, o, 64);
        if (lane == 0) out[(size_t)r * 11 + c] = (float)(v + (double)bc[c]);
    }
}

// ---------------------------------------------------------------------------
// launch
// ---------------------------------------------------------------------------
extern "C" void kernel_launch(void* const* d_in, const int* in_sizes, int n_in,
                              void* d_out, int out_size, void* d_ws, size_t ws_size,
                              hipStream_t stream) {
    const float* f0  = (const float*)d_in[0];
    const float* f1  = (const float*)d_in[1];
    const int*   ei  = (const int*)d_in[2];
    const float* Wr  = (const float*)d_in[3];
    const float* Wn  = (const float*)d_in[4];
    const float* b   = (const float*)d_in[5];
    const float* Wpr = (const float*)d_in[6];
    const float* Wpn = (const float*)d_in[7];
    const float* bp  = (const float*)d_in[8];
    const float* Wc  = (const float*)d_in[9];
    const float* bc  = (const float*)d_in[10];
    float* out = (float*)d_out;

    const int N = in_sizes[0] / 128;   // 32768
    const int E = in_sizes[2] / 2;     // 524288
    const int K = (N + 1) / 2;         // 16384
    const int L = in_sizes[5] / 256;   // 3 layers

    const int* src = ei;
    const int* dst = ei + E;

    // workspace layout (256B aligned slices)
    char* p = (char*)d_ws;
    auto take = [&](size_t bytes) {
        char* r = p;
        p += (bytes + 255) & ~(size_t)255;
        return r;
    };
    float*  xA      = (float*)take((size_t)N * 256 * 4);
    float*  xB      = (float*)take((size_t)N * 256 * 4);
    float*  agg     = (float*)take((size_t)N * 256 * 4);
    int*    counts  = (int*)take((size_t)N * 4);
    int*    offs    = (int*)take((size_t)(N + 1) * 4);
    int*    csr     = (int*)take((size_t)E * 4);
    double* sc      = (double*)take((size_t)N * 8);
    unsigned long long* keys = (unsigned long long*)take((size_t)N * 8);
    int*    rankcnt = (int*)take((size_t)N * 4);
    double* topd    = (double*)take((size_t)K * 8);
    int*    perm    = (int*)take((size_t)K * 4);
    double* yrv     = (double*)take((size_t)N * 8);
    double* ynv     = (double*)take((size_t)N * 8);
    (void)ws_size;

    hipMemsetAsync(counts, 0, (size_t)N * 4, stream);
    hipMemsetAsync(rankcnt, 0, (size_t)N * 4, stream);

    count_kernel<<<(E + 255) / 256, 256, 0, stream>>>(dst, counts, E);
    scan_kernel<<<1, 1024, 0, stream>>>(counts, offs, N, E);
    fill_kernel<<<(E + 255) / 256, 256, 0, stream>>>(dst, offs, counts, csr, E);
    bsort_kernel<<<(N + 255) / 256, 256, 0, stream>>>(csr, offs, src, N);

    // layer 0: virtual-concat inputs (no materialized x0)
    segsum_first_kernel<<<N / 4, 256, 0, stream>>>(f0, f1, csr, offs, agg, N);
    gemm_first_kernel<<<dim3(256 / GBN, N / GBM), 256, 0, stream>>>(
        f0, f1, agg, Wr, Wn, b, xB);

    float* xcur = xB;
    float* xnext = xA;
    for (int i = 1; i < L; ++i) {
        segsum_kernel<<<N / 4, 256, 0, stream>>>(xcur, csr, offs, agg, N);
        gemm_two_kernel<<<dim3(256 / GBN, N / GBM), 256, 0, stream>>>(
            xcur, agg, Wr + (size_t)i * 65536, Wn + (size_t)i * 65536,
            b + (size_t)i * 256, xnext);
        float* tmp = xcur; xcur = xnext; xnext = tmp;
    }
    // xcur == x3
    dot_kernel<<<N / 4, 256, 0, stream>>>(xcur, Wpr, Wpn, yrv, ynv, N);
    score_gather_kernel<<<N / 256, 256, 0, stream>>>(yrv, ynv, csr, offs, bp, sc, keys, N);
    rank_count_kernel<<<dim3(N / RTJ, N / RTI), 256, 0, stream>>>(keys, rankcnt, N);
    rank_scatter_kernel<<<(N + 255) / 256, 256, 0, stream>>>(rankcnt, sc, perm, topd, N, K);
    out_kernel<<<K / 4, 256, 0, stream>>>(xcur, perm, topd, Wc, bc, out, K);
}

// Round 11
// 800.710 us; speedup vs baseline: 2.0938x; 1.0076x over previous
//
#include <hip/hip_runtime.h>
#include <hip/hip_bf16.h>
#include <math.h>
#include <stdint.h>

// N = 32768 nodes, D = 256 features, E = 524288 edges, L = 3 layers,
// K = 16384 (top-k), C = 11 classes.
// GEMM history: 4x(4x4) fused BK=32 @124 VGPR = 127us/layer (best so far).
//   - __launch_bounds__(256,4) clamp -> spill (r5, 1.2GB/dispatch)
//   - 16x8 microtile -> 200 VGPR, 11% occ, 169us (r7)
//   - LDS double-buffer -> 256 VGPR, spill, 420us+ (r8)
// r11 experiment: BK=64 single-buffer (halves barrier pairs 16->8; staged
// regs die at store so no dbuf-style VGPR blowup). A/B: layer1=k64, layer2=k32.

// ---------------------------------------------------------------------------
// 2a. histogram of dst
// ---------------------------------------------------------------------------
__global__ __launch_bounds__(256) void count_kernel(const int* __restrict__ dst,
                                                    int* __restrict__ counts, int E) {
    int e = blockIdx.x * blockDim.x + threadIdx.x;
    if (e < E) atomicAdd(&counts[dst[e]], 1);
}

// ---------------------------------------------------------------------------
// 2b. exclusive scan of counts -> offsets[N+1]; zero counts (reused as cursor)
// ---------------------------------------------------------------------------
__global__ __launch_bounds__(1024) void scan_kernel(int* __restrict__ counts,
                                                    int* __restrict__ offs,
                                                    int N, int E) {
    __shared__ int s[1024];
    int t = threadIdx.x;
    int base = t * 32;
    int local[32];
    int sum = 0;
    #pragma unroll
    for (int j = 0; j < 32; ++j) { local[j] = counts[base + j]; sum += local[j]; }
    s[t] = sum;
    __syncthreads();
    for (int off = 1; off < 1024; off <<= 1) {
        int other = (t >= off) ? s[t - off] : 0;
        __syncthreads();
        s[t] += other;
        __syncthreads();
    }
    int run = s[t] - sum;  // exclusive base for this thread
    #pragma unroll
    for (int j = 0; j < 32; ++j) {
        offs[base + j] = run;
        run += local[j];
        counts[base + j] = 0;   // reset: reused as cursor in fill_kernel
    }
    if (t == 1023) offs[N] = E;
}

// ---------------------------------------------------------------------------
// 2c. scatter edge ids into CSR buckets
// ---------------------------------------------------------------------------
__global__ __launch_bounds__(256) void fill_kernel(const int* __restrict__ dst,
                                                   const int* __restrict__ offs,
                                                   int* __restrict__ cursor,
                                                   int* __restrict__ csr, int E) {
    int e = blockIdx.x * blockDim.x + threadIdx.x;
    if (e >= E) return;
    int d = dst[e];
    int pos = offs[d] + atomicAdd(&cursor[d], 1);
    csr[pos] = e;
}

// ---------------------------------------------------------------------------
// 2d. per-bucket insertion sort by edge id (deterministic), map edge->src
// ---------------------------------------------------------------------------
__global__ __launch_bounds__(256) void bsort_kernel(int* __restrict__ csr,
                                                    const int* __restrict__ offs,
                                                    const int* __restrict__ src,
                                                    int N) {
    int i = blockIdx.x * blockDim.x + threadIdx.x;
    if (i >= N) return;
    int beg = offs[i], end = offs[i + 1];
    for (int a = beg + 1; a < end; ++a) {
        int v = csr[a];
        int b = a - 1;
        while (b >= beg && csr[b] > v) { csr[b + 1] = csr[b]; --b; }
        csr[b + 1] = v;
    }
    for (int p = beg; p < end; ++p) csr[p] = src[csr[p]];
}

// ---------------------------------------------------------------------------
// 3. segment sum: agg[n][:] = sum over csr bucket of x[src][:]
// ---------------------------------------------------------------------------
__global__ __launch_bounds__(256) void segsum_kernel(const float* __restrict__ X,
                                                     const int* __restrict__ csr,
                                                     const int* __restrict__ offs,
                                                     float* __restrict__ AGG, int N) {
    int w = threadIdx.x >> 6;
    int lane = threadIdx.x & 63;
    int n = blockIdx.x * 4 + w;
    if (n >= N) return;
    int beg = offs[n], end = offs[n + 1];
    float4 acc = make_float4(0.f, 0.f, 0.f, 0.f);
    for (int p = beg; p < end; ++p) {
        int s = csr[p];
        float4 v = *(const float4*)(X + (size_t)s * 256 + lane * 4);
        acc.x += v.x; acc.y += v.y; acc.z += v.z; acc.w += v.w;
    }
    *(float4*)(AGG + (size_t)n * 256 + lane * 4) = acc;
}

// ---------------------------------------------------------------------------
// 3f. first-layer segment sum: x0 = [f0|f1] virtual concat (col<128 -> f0).
// ---------------------------------------------------------------------------
__global__ __launch_bounds__(256) void segsum_first_kernel(
        const float* __restrict__ f0, const float* __restrict__ f1,
        const int* __restrict__ csr, const int* __restrict__ offs,
        float* __restrict__ AGG, int N) {
    int w = threadIdx.x >> 6;
    int lane = threadIdx.x & 63;
    int n = blockIdx.x * 4 + w;
    if (n >= N) return;
    const float* base = (lane < 32) ? (f0 + lane * 4) : (f1 + (lane - 32) * 4);
    int beg = offs[n], end = offs[n + 1];
    float4 acc = make_float4(0.f, 0.f, 0.f, 0.f);
    for (int p = beg; p < end; ++p) {
        int s = csr[p];
        float4 v = *(const float4*)(base + (size_t)s * 128);
        acc.x += v.x; acc.y += v.y; acc.z += v.z; acc.w += v.w;
    }
    *(float4*)(AGG + (size_t)n * 256 + lane * 4) = acc;
}

// ---------------------------------------------------------------------------
// 4. fused GEMM: Y = relu(X @ W1 + G @ W2 + bias)   [N,512-split] x [512,256]
//    128x128 tile, 256 threads, 4x(4x4) quadrant micro-tile.
// ---------------------------------------------------------------------------
#define GBM 128
#define GBN 128
#define GBK 32

__device__ __forceinline__ float4 ldA01(const float* __restrict__ f0,
                                        const float* __restrict__ f1,
                                        int row, int c) {
    return (c < 128) ? *(const float4*)(f0 + (size_t)row * 128 + c)
                     : *(const float4*)(f1 + (size_t)row * 128 + (c - 128));
}

#define GEMM_W_LOAD(Wsrc, kloc)                                                      \
    {                                                                                \
        w_st0 = *(const float4*)((Wsrc) + (size_t)((kloc) + wk) * 256 + colBase + wc);     \
        w_st1 = *(const float4*)((Wsrc) + (size_t)((kloc) + wk + 8) * 256 + colBase + wc); \
        w_st2 = *(const float4*)((Wsrc) + (size_t)((kloc) + wk + 16) * 256 + colBase + wc);\
        w_st3 = *(const float4*)((Wsrc) + (size_t)((kloc) + wk + 24) * 256 + colBase + wc);\
    }

#define GEMM_LOAD_STAGE(kt)                                                          \
    {                                                                                \
        const int kb = (kt) * GBK;                                                   \
        const float* Asrc = (kb < 256) ? X : G;                                      \
        const float* Wsrc = (kb < 256) ? W1 : W2;                                    \
        const int kloc = kb & 255;                                                   \
        a_st0 = *(const float4*)(Asrc + (size_t)(rowBase + ar) * 256 + kloc + ak);   \
        a_st1 = *(const float4*)(Asrc + (size_t)(rowBase + ar + 64) * 256 + kloc + ak); \
        a_st2 = *(const float4*)(Asrc + (size_t)(rowBase + ar) * 256 + kloc + 16 + ak); \
        a_st3 = *(const float4*)(Asrc + (size_t)(rowBase + ar + 64) * 256 + kloc + 16 + ak); \
        GEMM_W_LOAD(Wsrc, kloc)                                                      \
    }

#define GEMM_LOAD_STAGE_F(kt)                                                        \
    {                                                                                \
        const int kb = (kt) * GBK;                                                   \
        if (kb < 256) {                                                              \
            a_st0 = ldA01(f0, f1, rowBase + ar,      kb + ak);                       \
            a_st1 = ldA01(f0, f1, rowBase + ar + 64, kb + ak);                       \
            a_st2 = ldA01(f0, f1, rowBase + ar,      kb + 16 + ak);                  \
            a_st3 = ldA01(f0, f1, rowBase + ar + 64, kb + 16 + ak);                  \
            GEMM_W_LOAD(W1, kb)                                                      \
        } else {                                                                     \
            const int kloc = kb & 255;                                               \
            a_st0 = *(const float4*)(G + (size_t)(rowBase + ar) * 256 + kloc + ak);  \
            a_st1 = *(const float4*)(G + (size_t)(rowBase + ar + 64) * 256 + kloc + ak); \
            a_st2 = *(const float4*)(G + (size_t)(rowBase + ar) * 256 + kloc + 16 + ak); \
            a_st3 = *(const float4*)(G + (size_t)(rowBase + ar + 64) * 256 + kloc + 16 + ak); \
            GEMM_W_LOAD(W2, kloc)                                                    \
        }                                                                            \
    }

#define GEMM_STORE_STAGE()                                                           \
    {                                                                                \
        _Pragma("unroll")                                                            \
        for (int j = 0; j < 4; ++j) {                                                \
            As[ak + j][ar]           = ((const float*)&a_st0)[j];                    \
            As[ak + j][ar + 64]      = ((const float*)&a_st1)[j];                    \
            As[16 + ak + j][ar]      = ((const float*)&a_st2)[j];                    \
            As[16 + ak + j][ar + 64] = ((const float*)&a_st3)[j];                    \
        }                                                                            \
        *(float4*)&Ws[wk][wc]      = w_st0;                                          \
        *(float4*)&Ws[wk + 8][wc]  = w_st1;                                          \
        *(float4*)&Ws[wk + 16][wc] = w_st2;                                          \
        *(float4*)&Ws[wk + 24][wc] = w_st3;                                          \
    }

#define GEMM_COMPUTE(BKN)                                                            \
    {                                                                                \
        _Pragma("unroll")                                                            \
        for (int kk = 0; kk < BKN; ++kk) {                                           \
            float a0[4], a1[4], w0[4], w1[4];                                        \
            *(float4*)a0 = *(const float4*)&As[kk][trow * 4];                        \
            *(float4*)a1 = *(const float4*)&As[kk][64 + trow * 4];                   \
            *(float4*)w0 = *(const float4*)&Ws[kk][tcol * 4];                        \
            *(float4*)w1 = *(const float4*)&Ws[kk][64 + tcol * 4];                   \
            _Pragma("unroll")                                                        \
            for (int i = 0; i < 4; ++i)                                              \
                _Pragma("unroll")                                                    \
                for (int j = 0; j < 4; ++j) {                                        \
                    acc[0][i][j] = fmaf(a0[i], w0[j], acc[0][i][j]);                 \
                    acc[1][i][j] = fmaf(a0[i], w1[j], acc[1][i][j]);                 \
                    acc[2][i][j] = fmaf(a1[i], w0[j], acc[2][i][j]);                 \
                    acc[3][i][j] = fmaf(a1[i], w1[j], acc[3][i][j]);                 \
                }                                                                    \
        }                                                                            \
    }

#define GEMM_EPILOGUE()                                                              \
    {                                                                                \
        _Pragma("unroll")                                                            \
        for (int h = 0; h < 2; ++h) {                                                \
            _Pragma("unroll")                                                        \
            for (int i = 0; i < 4; ++i) {                                            \
                const int row = rowBase + h * 64 + trow * 4 + i;                     \
                _Pragma("unroll")                                                    \
                for (int g = 0; g < 2; ++g) {                                        \
                    const int colb = colBase + g * 64 + tcol * 4;                    \
                    float o[4];                                                      \
                    _Pragma("unroll")                                                \
                    for (int j = 0; j < 4; ++j)                                      \
                        o[j] = fmaxf(acc[h * 2 + g][i][j] + bias[colb + j], 0.f);    \
                    *(float4*)(Y + (size_t)row * 256 + colb) = *(const float4*)&o[0];\
                }                                                                    \
            }                                                                        \
        }                                                                            \
    }

#define GEMM_PREAMBLE(BKN)                                                           \
    __shared__ float As[BKN][GBM + 4];                                               \
    __shared__ float Ws[BKN][GBN + 4];                                               \
    const int tid = threadIdx.x;                                                     \
    const int tcol = tid & 15;                                                       \
    const int trow = tid >> 4;                                                       \
    const int rowBase = blockIdx.y * GBM;                                            \
    const int colBase = blockIdx.x * GBN;                                            \
    const int ar = tid >> 2;                                                         \
    const int ak = (tid & 3) * 4;                                                    \
    const int wk = tid >> 5;                                                         \
    const int wc = (tid & 31) * 4;                                                   \
    float acc[4][4][4];                                                              \
    _Pragma("unroll")                                                                \
    for (int q = 0; q < 4; ++q)                                                      \
        _Pragma("unroll")                                                            \
        for (int i = 0; i < 4; ++i)                                                  \
            _Pragma("unroll")                                                        \
            for (int j = 0; j < 4; ++j) acc[q][i][j] = 0.f;

__global__ __launch_bounds__(256) void gemm_two_kernel(const float* __restrict__ X,
                                                       const float* __restrict__ G,
                                                       const float* __restrict__ W1,
                                                       const float* __restrict__ W2,
                                                       const float* __restrict__ bias,
                                                       float* __restrict__ Y) {
    GEMM_PREAMBLE(GBK);
    float4 a_st0, a_st1, a_st2, a_st3, w_st0, w_st1, w_st2, w_st3;
    GEMM_LOAD_STAGE(0);
    for (int kt = 0; kt < 512 / GBK; ++kt) {
        __syncthreads();   // previous tile fully consumed
        GEMM_STORE_STAGE();
        __syncthreads();
        if (kt < 512 / GBK - 1) GEMM_LOAD_STAGE(kt + 1);  // overlap with compute
        GEMM_COMPUTE(GBK);
    }
    GEMM_EPILOGUE();
}

// ------------------- BK=64 experimental variant (r11 A/B) -------------------
#define GBK64 64

#define GEMM_LOAD_STAGE64(kt)                                                        \
    {                                                                                \
        const int kb = (kt) * GBK64;                                                 \
        const float* Asrc = (kb < 256) ? X : G;                                      \
        const float* Wsrc = (kb < 256) ? W1 : W2;                                    \
        const int kloc = kb & 255;                                                   \
        const float* Ab0 = Asrc + (size_t)(rowBase + ar) * 256 + kloc + ak;          \
        const float* Ab1 = Asrc + (size_t)(rowBase + ar + 64) * 256 + kloc + ak;     \
        a_st0 = *(const float4*)(Ab0);                                               \
        a_st1 = *(const float4*)(Ab1);                                               \
        a_st2 = *(const float4*)(Ab0 + 16);                                          \
        a_st3 = *(const float4*)(Ab1 + 16);                                          \
        a_st4 = *(const float4*)(Ab0 + 32);                                          \
        a_st5 = *(const float4*)(Ab1 + 32);                                          \
        a_st6 = *(const float4*)(Ab0 + 48);                                          \
        a_st7 = *(const float4*)(Ab1 + 48);                                          \
        const float* Wb = Wsrc + (size_t)(kloc + wk) * 256 + colBase + wc;           \
        w_st0 = *(const float4*)(Wb);                                                \
        w_st1 = *(const float4*)(Wb + 8 * 256);                                      \
        w_st2 = *(const float4*)(Wb + 16 * 256);                                     \
        w_st3 = *(const float4*)(Wb + 24 * 256);                                     \
        w_st4 = *(const float4*)(Wb + 32 * 256);                                     \
        w_st5 = *(const float4*)(Wb + 40 * 256);                                     \
        w_st6 = *(const float4*)(Wb + 48 * 256);                                     \
        w_st7 = *(const float4*)(Wb + 56 * 256);                                     \
    }

#define GEMM_STORE_STAGE64()                                                         \
    {                                                                                \
        _Pragma("unroll")                                                            \
        for (int j = 0; j < 4; ++j) {                                                \
            As[ak + j][ar]           = ((const float*)&a_st0)[j];                    \
            As[ak + j][ar + 64]      = ((const float*)&a_st1)[j];                    \
            As[16 + ak + j][ar]      = ((const float*)&a_st2)[j];                    \
            As[16 + ak + j][ar + 64] = ((const float*)&a_st3)[j];                    \
            As[32 + ak + j][ar]      = ((const float*)&a_st4)[j];                    \
            As[32 + ak + j][ar + 64] = ((const float*)&a_st5)[j];                    \
            As[48 + ak + j][ar]      = ((const float*)&a_st6)[j];                    \
            As[48 + ak + j][ar + 64] = ((const float*)&a_st7)[j];                    \
        }                                                                            \
        *(float4*)&Ws[wk][wc]      = w_st0;                                          \
        *(float4*)&Ws[wk + 8][wc]  = w_st1;                                          \
        *(float4*)&Ws[wk + 16][wc] = w_st2;                                          \
        *(float4*)&Ws[wk + 24][wc] = w_st3;                                          \
        *(float4*)&Ws[wk + 32][wc] = w_st4;                                          \
        *(float4*)&Ws[wk + 40][wc] = w_st5;                                          \
        *(float4*)&Ws[wk + 48][wc] = w_st6;                                          \
        *(float4*)&Ws[wk + 56][wc] = w_st7;                                          \
    }

__global__ __launch_bounds__(256) void gemm_two_k64_kernel(
        const float* __restrict__ X, const float* __restrict__ G,
        const float* __restrict__ W1, const float* __restrict__ W2,
        const float* __restrict__ bias, float* __restrict__ Y) {
    GEMM_PREAMBLE(GBK64);
    float4 a_st0, a_st1, a_st2, a_st3, a_st4, a_st5, a_st6, a_st7;
    float4 w_st0, w_st1, w_st2, w_st3, w_st4, w_st5, w_st6, w_st7;
    GEMM_LOAD_STAGE64(0);
    for (int kt = 0; kt < 512 / GBK64; ++kt) {
        __syncthreads();
        GEMM_STORE_STAGE64();
        __syncthreads();
        if (kt < 512 / GBK64 - 1) GEMM_LOAD_STAGE64(kt + 1);
        GEMM_COMPUTE(GBK64);
    }
    GEMM_EPILOGUE();
}

// first layer: X = virtual concat of f0|f1 (concat kernel eliminated)
__global__ __launch_bounds__(256) void gemm_first_kernel(const float* __restrict__ f0,
                                                         const float* __restrict__ f1,
                                                         const float* __restrict__ G,
                                                         const float* __restrict__ W1,
                                                         const float* __restrict__ W2,
                                                         const float* __restrict__ bias,
                                                         float* __restrict__ Y) {
    GEMM_PREAMBLE(GBK);
    float4 a_st0, a_st1, a_st2, a_st3, w_st0, w_st1, w_st2, w_st3;
    GEMM_LOAD_STAGE_F(0);
    for (int kt = 0; kt < 512 / GBK; ++kt) {
        __syncthreads();
        GEMM_STORE_STAGE();
        __syncthreads();
        if (kt < 512 / GBK - 1) GEMM_LOAD_STAGE_F(kt + 1);
        GEMM_COMPUTE(GBK);
    }
    GEMM_EPILOGUE();
}

// ---------------------------------------------------------------------------
// 5a. per-node dots: yr[n] = x3[n].Wpr, yn[n] = x3[n].Wpn   (f64)
// ---------------------------------------------------------------------------
__global__ __launch_bounds__(256) void dot_kernel(const float* __restrict__ X3,
                                                  const float* __restrict__ Wpr,
                                                  const float* __restrict__ Wpn,
                                                  double* __restrict__ yr,
                                                  double* __restrict__ yn, int N) {
    int w = threadIdx.x >> 6;
    int lane = threadIdx.x & 63;
    int n = blockIdx.x * 4 + w;
    if (n >= N) return;
    float4 xv = *(const float4*)(X3 + (size_t)n * 256 + lane * 4);
    float4 wr = *(const float4*)(Wpr + lane * 4);
    float4 wn = *(const float4*)(Wpn + lane * 4);
    double dr = (double)xv.x * wr.x + (double)xv.y * wr.y +
                (double)xv.z * wr.z + (double)xv.w * wr.w;
    double dn = (double)xv.x * wn.x + (double)xv.y * wn.y +
                (double)xv.z * wn.z + (double)xv.w * wn.w;
    #pragma unroll
    for (int o = 32; o > 0; o >>= 1) {
        dr += __shfl_down(dr, o, 64);
        dn += __shfl_down(dn, o, 64);
    }
    if (lane == 0) { yr[n] = dr; yn[n] = dn; }
}

// ---------------------------------------------------------------------------
// 5b. score[n] = yr[n] + sum_{bucket} yn[src] + bp; emit order-preserving key
// ---------------------------------------------------------------------------
__global__ __launch_bounds__(256) void score_gather_kernel(
        const double* __restrict__ yr, const double* __restrict__ yn,
        const int* __restrict__ csr, const int* __restrict__ offs,
        const float* __restrict__ bp,
        double* __restrict__ sc, unsigned long long* __restrict__ keys, int N) {
    int n = blockIdx.x * blockDim.x + threadIdx.x;
    if (n >= N) return;
    double s = yr[n] + (double)bp[0];
    int beg = offs[n], end = offs[n + 1];
    for (int p = beg; p < end; ++p) s += yn[csr[p]];
    sc[n] = s;
    long long sb = __double_as_longlong(s);
    keys[n] = (sb < 0) ? ~(unsigned long long)sb
                       : ((unsigned long long)sb | 0x8000000000000000ULL);
}

// ---------------------------------------------------------------------------
// 6a. tiled exact rank-count on uint64 keys.
// ---------------------------------------------------------------------------
#define RTI 1024
#define RTJ 512
__global__ __launch_bounds__(256) void rank_count_kernel(
        const unsigned long long* __restrict__ keys,
        int* __restrict__ rankcnt, int N) {
    __shared__ __align__(16) unsigned long long sk[RTJ];
    const int tid = threadIdx.x;
    const int ibase = blockIdx.y * RTI;
    const int jbase = blockIdx.x * RTJ;

    unsigned long long ki[4];
    #pragma unroll
    for (int r = 0; r < 4; ++r) ki[r] = keys[ibase + r * 256 + tid];
    for (int t = tid; t < RTJ; t += 256) sk[t] = keys[jbase + t];
    __syncthreads();

    int cnt[4] = {0, 0, 0, 0};
    if (jbase + RTJ <= ibase) {
        for (int u = 0; u < RTJ; u += 8) {
            ulonglong2 p0 = *(const ulonglong2*)&sk[u];
            ulonglong2 p1 = *(const ulonglong2*)&sk[u + 2];
            ulonglong2 p2 = *(const ulonglong2*)&sk[u + 4];
            ulonglong2 p3 = *(const ulonglong2*)&sk[u + 6];
            #pragma unroll
            for (int r = 0; r < 4; ++r) {
                cnt[r] += (int)(p0.x >= ki[r]) + (int)(p0.y >= ki[r])
                        + (int)(p1.x >= ki[r]) + (int)(p1.y >= ki[r])
                        + (int)(p2.x >= ki[r]) + (int)(p2.y >= ki[r])
                        + (int)(p3.x >= ki[r]) + (int)(p3.y >= ki[r]);
            }
        }
    } else if (jbase >= ibase + RTI) {
        for (int u = 0; u < RTJ; u += 8) {
            ulonglong2 p0 = *(const ulonglong2*)&sk[u];
            ulonglong2 p1 = *(const ulonglong2*)&sk[u + 2];
            ulonglong2 p2 = *(const ulonglong2*)&sk[u + 4];
            ulonglong2 p3 = *(const ulonglong2*)&sk[u + 6];
            #pragma unroll
            for (int r = 0; r < 4; ++r) {
                cnt[r] += (int)(p0.x > ki[r]) + (int)(p0.y > ki[r])
                        + (int)(p1.x > ki[r]) + (int)(p1.y > ki[r])
                        + (int)(p2.x > ki[r]) + (int)(p2.y > ki[r])
                        + (int)(p3.x > ki[r]) + (int)(p3.y > ki[r]);
            }
        }
    } else {
        int thr[4];
        #pragma unroll
        for (int r = 0; r < 4; ++r) thr[r] = ibase + r * 256 + tid - jbase;
        for (int u = 0; u < RTJ; ++u) {
            unsigned long long kj = sk[u];
            #pragma unroll
            for (int r = 0; r < 4; ++r)
                cnt[r] += (kj > ki[r]) || (kj == ki[r] && u < thr[r]);
        }
    }
    #pragma unroll
    for (int r = 0; r < 4; ++r)
        atomicAdd(&rankcnt[ibase + r * 256 + tid], cnt[r]);
}

// ---------------------------------------------------------------------------
// 6b. scatter by rank
// ---------------------------------------------------------------------------
__global__ __launch_bounds__(256) void rank_scatter_kernel(
        const int* __restrict__ rankcnt,
        const double* __restrict__ sc,
        int* __restrict__ perm,
        double* __restrict__ topd, int N, int K) {
    int i = blockIdx.x * blockDim.x + threadIdx.x;
    if (i >= N) return;
    int rank = rankcnt[i];
    if (rank < K) { perm[rank] = i; topd[rank] = sc[i]; }
}

// ---------------------------------------------------------------------------
// 7. head: out[r] = relu(x3[perm[r]] * tanh(score_r)) @ Wc + bc  (f64 accum)
// ---------------------------------------------------------------------------
__global__ __launch_bounds__(256) void out_kernel(const float* __restrict__ X3,
                                                  const int* __restrict__ perm,
                                                  const double* __restrict__ topd,
                                                  const float* __restrict__ Wc,
                                                  const float* __restrict__ bc,
                                                  float* __restrict__ out, int K) {
    int w = threadIdx.x >> 6;
    int lane = threadIdx.x & 63;
    int r = blockIdx.x * 4 + w;
    if (r >= K) return;
    int p = perm[r];
    double t = tanh(topd[r]);
    float4 xv = *(const float4*)(X3 + (size_t)p * 256 + lane * 4);
    double xp[4];
    xp[0] = (double)xv.x * t; xp[1] = (double)xv.y * t;
    xp[2] = (double)xv.z * t; xp[3] = (double)xv.w * t;
    #pragma unroll
    for (int j = 0; j < 4; ++j) xp[j] = xp[j] > 0.0 ? xp[j] : 0.0;
    double acc[11];
    #pragma unroll
    for (int c = 0; c < 11; ++c) acc[c] = 0.0;
    #pragma unroll
    for (int j = 0; j < 4; ++j) {
        const float* wrow = Wc + (size_t)(lane * 4 + j) * 11;
        #pragma unroll
        for (int c = 0; c < 11; ++c) acc[c] += xp[j] * (double)wrow[c];
    }
    #pragma unroll
    for (int c = 0; c < 11; ++c) {
        double v = acc[c];
        #pragma unroll
        for (int o = 32; o > 0; o >>= 1) v += __shfl_down(v, o, 64);
        if (lane == 0) out[(size_t)r * 11 + c] = (float)(v + (double)bc[c]);
    }
}

// ---------------------------------------------------------------------------
// launch
// ---------------------------------------------------------------------------
extern "C" void kernel_launch(void* const* d_in, const int* in_sizes, int n_in,
                              void* d_out, int out_size, void* d_ws, size_t ws_size,
                              hipStream_t stream) {
    const float* f0  = (const float*)d_in[0];
    const float* f1  = (const float*)d_in[1];
    const int*   ei  = (const int*)d_in[2];
    const float* Wr  = (const float*)d_in[3];
    const float* Wn  = (const float*)d_in[4];
    const float* b   = (const float*)d_in[5];
    const float* Wpr = (const float*)d_in[6];
    const float* Wpn = (const float*)d_in[7];
    const float* bp  = (const float*)d_in[8];
    const float* Wc  = (const float*)d_in[9];
    const float* bc  = (const float*)d_in[10];
    float* out = (float*)d_out;

    const int N = in_sizes[0] / 128;   // 32768
    const int E = in_sizes[2] / 2;     // 524288
    const int K = (N + 1) / 2;         // 16384
    const int L = in_sizes[5] / 256;   // 3 layers

    const int* src = ei;
    const int* dst = ei + E;

    // workspace layout (256B aligned slices)
    char* p = (char*)d_ws;
    auto take = [&](size_t bytes) {
        char* r = p;
        p += (bytes + 255) & ~(size_t)255;
        return r;
    };
    float*  xA      = (float*)take((size_t)N * 256 * 4);
    float*  xB      = (float*)take((size_t)N * 256 * 4);
    float*  agg     = (float*)take((size_t)N * 256 * 4);
    int*    counts  = (int*)take((size_t)N * 4);
    int*    offs    = (int*)take((size_t)(N + 1) * 4);
    int*    csr     = (int*)take((size_t)E * 4);
    double* sc      = (double*)take((size_t)N * 8);
    unsigned long long* keys = (unsigned long long*)take((size_t)N * 8);
    int*    rankcnt = (int*)take((size_t)N * 4);
    double* topd    = (double*)take((size_t)K * 8);
    int*    perm    = (int*)take((size_t)K * 4);
    double* yrv     = (double*)take((size_t)N * 8);
    double* ynv     = (double*)take((size_t)N * 8);
    (void)ws_size;

    hipMemsetAsync(counts, 0, (size_t)N * 4, stream);
    hipMemsetAsync(rankcnt, 0, (size_t)N * 4, stream);

    count_kernel<<<(E + 255) / 256, 256, 0, stream>>>(dst, counts, E);
    scan_kernel<<<1, 1024, 0, stream>>>(counts, offs, N, E);
    fill_kernel<<<(E + 255) / 256, 256, 0, stream>>>(dst, offs, counts, csr, E);
    bsort_kernel<<<(N + 255) / 256, 256, 0, stream>>>(csr, offs, src, N);

    // layer 0: virtual-concat inputs (no materialized x0)
    segsum_first_kernel<<<N / 4, 256, 0, stream>>>(f0, f1, csr, offs, agg, N);
    gemm_first_kernel<<<dim3(256 / GBN, N / GBM), 256, 0, stream>>>(
        f0, f1, agg, Wr, Wn, b, xB);

    // layer 1: BK=64 experimental (A/B vs layer 2's BK=32; identical math)
    segsum_kernel<<<N / 4, 256, 0, stream>>>(xB, csr, offs, agg, N);
    gemm_two_k64_kernel<<<dim3(256 / GBN, N / GBM), 256, 0, stream>>>(
        xB, agg, Wr + 65536, Wn + 65536, b + 256, xA);

    // layer 2: BK=32 reference
    segsum_kernel<<<N / 4, 256, 0, stream>>>(xA, csr, offs, agg, N);
    gemm_two_kernel<<<dim3(256 / GBN, N / GBM), 256, 0, stream>>>(
        xA, agg, Wr + 2 * 65536, Wn + 2 * 65536, b + 2 * 256, xB);

    float* xcur = xB;  // x3
    dot_kernel<<<N / 4, 256, 0, stream>>>(xcur, Wpr, Wpn, yrv, ynv, N);
    score_gather_kernel<<<N / 256, 256, 0, stream>>>(yrv, ynv, csr, offs, bp, sc, keys, N);
    rank_count_kernel<<<dim3(N / RTJ, N / RTI), 256, 0, stream>>>(keys, rankcnt, N);
    rank_scatter_kernel<<<(N + 255) / 256, 256, 0, stream>>>(rankcnt, sc, perm, topd, N, K);
    out_kernel<<<K / 4, 256, 0, stream>>>(xcur, perm, topd, Wc, bc, out, K);
}

// Round 12
// 788.570 us; speedup vs baseline: 2.1261x; 1.0154x over previous
//
#include <hip/hip_runtime.h>
#include <hip/hip_bf16.h>
#include <math.h>
#include <stdint.h>

// N = 32768 nodes, D = 256 features, E = 524288 edges, L = 3 layers,
// K = 16384 (top-k), C = 11 classes.
// GEMM history (per-layer dispatch time):
//   BK=32 4x(4x4) fused, 124-128 VGPR ........ 127 us
//   __launch_bounds__(256,4) clamp ........... spill, 1.2GB/dispatch (r5)
//   16x8 microtile ........................... 200 VGPR, 11% occ, 169 us (r7)
//   LDS double-buffer ........................ 256 VGPR, spill, 420+ us (r8)
//   BK=64 single-buffer (r11 A/B) ............ ~121 us  <- ADOPTED (r12)
// BK=64 halves barrier pairs (16->8); staged regs die at the LDS store so
// VGPR stays in the no-spill tier (unlike dbuf which keeps them live).

// ---------------------------------------------------------------------------
// 2a. histogram of dst
// ---------------------------------------------------------------------------
__global__ __launch_bounds__(256) void count_kernel(const int* __restrict__ dst,
                                                    int* __restrict__ counts, int E) {
    int e = blockIdx.x * blockDim.x + threadIdx.x;
    if (e < E) atomicAdd(&counts[dst[e]], 1);
}

// ---------------------------------------------------------------------------
// 2b. exclusive scan of counts -> offsets[N+1]; zero counts (reused as cursor)
// ---------------------------------------------------------------------------
__global__ __launch_bounds__(1024) void scan_kernel(int* __restrict__ counts,
                                                    int* __restrict__ offs,
                                                    int N, int E) {
    __shared__ int s[1024];
    int t = threadIdx.x;
    int base = t * 32;
    int local[32];
    int sum = 0;
    #pragma unroll
    for (int j = 0; j < 32; ++j) { local[j] = counts[base + j]; sum += local[j]; }
    s[t] = sum;
    __syncthreads();
    for (int off = 1; off < 1024; off <<= 1) {
        int other = (t >= off) ? s[t - off] : 0;
        __syncthreads();
        s[t] += other;
        __syncthreads();
    }
    int run = s[t] - sum;  // exclusive base for this thread
    #pragma unroll
    for (int j = 0; j < 32; ++j) {
        offs[base + j] = run;
        run += local[j];
        counts[base + j] = 0;   // reset: reused as cursor in fill_kernel
    }
    if (t == 1023) offs[N] = E;
}

// ---------------------------------------------------------------------------
// 2c. scatter edge ids into CSR buckets
// ---------------------------------------------------------------------------
__global__ __launch_bounds__(256) void fill_kernel(const int* __restrict__ dst,
                                                   const int* __restrict__ offs,
                                                   int* __restrict__ cursor,
                                                   int* __restrict__ csr, int E) {
    int e = blockIdx.x * blockDim.x + threadIdx.x;
    if (e >= E) return;
    int d = dst[e];
    int pos = offs[d] + atomicAdd(&cursor[d], 1);
    csr[pos] = e;
}

// ---------------------------------------------------------------------------
// 2d. per-bucket insertion sort by edge id (deterministic), map edge->src
// ---------------------------------------------------------------------------
__global__ __launch_bounds__(256) void bsort_kernel(int* __restrict__ csr,
                                                    const int* __restrict__ offs,
                                                    const int* __restrict__ src,
                                                    int N) {
    int i = blockIdx.x * blockDim.x + threadIdx.x;
    if (i >= N) return;
    int beg = offs[i], end = offs[i + 1];
    for (int a = beg + 1; a < end; ++a) {
        int v = csr[a];
        int b = a - 1;
        while (b >= beg && csr[b] > v) { csr[b + 1] = csr[b]; --b; }
        csr[b + 1] = v;
    }
    for (int p = beg; p < end; ++p) csr[p] = src[csr[p]];
}

// ---------------------------------------------------------------------------
// 3. segment sum: agg[n][:] = sum over csr bucket of x[src][:]
// ---------------------------------------------------------------------------
__global__ __launch_bounds__(256) void segsum_kernel(const float* __restrict__ X,
                                                     const int* __restrict__ csr,
                                                     const int* __restrict__ offs,
                                                     float* __restrict__ AGG, int N) {
    int w = threadIdx.x >> 6;
    int lane = threadIdx.x & 63;
    int n = blockIdx.x * 4 + w;
    if (n >= N) return;
    int beg = offs[n], end = offs[n + 1];
    float4 acc = make_float4(0.f, 0.f, 0.f, 0.f);
    for (int p = beg; p < end; ++p) {
        int s = csr[p];
        float4 v = *(const float4*)(X + (size_t)s * 256 + lane * 4);
        acc.x += v.x; acc.y += v.y; acc.z += v.z; acc.w += v.w;
    }
    *(float4*)(AGG + (size_t)n * 256 + lane * 4) = acc;
}

// ---------------------------------------------------------------------------
// 3f. first-layer segment sum: x0 = [f0|f1] virtual concat (col<128 -> f0).
// ---------------------------------------------------------------------------
__global__ __launch_bounds__(256) void segsum_first_kernel(
        const float* __restrict__ f0, const float* __restrict__ f1,
        const int* __restrict__ csr, const int* __restrict__ offs,
        float* __restrict__ AGG, int N) {
    int w = threadIdx.x >> 6;
    int lane = threadIdx.x & 63;
    int n = blockIdx.x * 4 + w;
    if (n >= N) return;
    const float* base = (lane < 32) ? (f0 + lane * 4) : (f1 + (lane - 32) * 4);
    int beg = offs[n], end = offs[n + 1];
    float4 acc = make_float4(0.f, 0.f, 0.f, 0.f);
    for (int p = beg; p < end; ++p) {
        int s = csr[p];
        float4 v = *(const float4*)(base + (size_t)s * 128);
        acc.x += v.x; acc.y += v.y; acc.z += v.z; acc.w += v.w;
    }
    *(float4*)(AGG + (size_t)n * 256 + lane * 4) = acc;
}

// ---------------------------------------------------------------------------
// 4. fused GEMM: Y = relu(X @ W1 + G @ W2 + bias)   [N,512-split] x [512,256]
//    128x128 tile, BK=64, 256 threads, 4x(4x4) quadrant micro-tile,
//    single LDS buffer, 8 barrier pairs per block.
// ---------------------------------------------------------------------------
#define GBM 128
#define GBN 128
#define GBK64 64

#define GEMM_W_LOAD64(Wsrc, kloc)                                                    \
    {                                                                                \
        const float* Wb = (Wsrc) + (size_t)((kloc) + wk) * 256 + colBase + wc;       \
        w_st0 = *(const float4*)(Wb);                                                \
        w_st1 = *(const float4*)(Wb + 8 * 256);                                      \
        w_st2 = *(const float4*)(Wb + 16 * 256);                                     \
        w_st3 = *(const float4*)(Wb + 24 * 256);                                     \
        w_st4 = *(const float4*)(Wb + 32 * 256);                                     \
        w_st5 = *(const float4*)(Wb + 40 * 256);                                     \
        w_st6 = *(const float4*)(Wb + 48 * 256);                                     \
        w_st7 = *(const float4*)(Wb + 56 * 256);                                     \
    }

#define GEMM_A_LOAD64(Ab0, Ab1)                                                      \
    {                                                                                \
        a_st0 = *(const float4*)(Ab0);                                               \
        a_st1 = *(const float4*)(Ab1);                                               \
        a_st2 = *(const float4*)((Ab0) + 16);                                        \
        a_st3 = *(const float4*)((Ab1) + 16);                                        \
        a_st4 = *(const float4*)((Ab0) + 32);                                        \
        a_st5 = *(const float4*)((Ab1) + 32);                                        \
        a_st6 = *(const float4*)((Ab0) + 48);                                        \
        a_st7 = *(const float4*)((Ab1) + 48);                                        \
    }

#define GEMM_LOAD_STAGE64(kt)                                                        \
    {                                                                                \
        const int kb = (kt) * GBK64;                                                 \
        const float* Asrc = (kb < 256) ? X : G;                                      \
        const float* Wsrc = (kb < 256) ? W1 : W2;                                    \
        const int kloc = kb & 255;                                                   \
        const float* Ab0 = Asrc + (size_t)(rowBase + ar) * 256 + kloc + ak;          \
        const float* Ab1 = Asrc + (size_t)(rowBase + ar + 64) * 256 + kloc + ak;     \
        GEMM_A_LOAD64(Ab0, Ab1)                                                      \
        GEMM_W_LOAD64(Wsrc, kloc)                                                    \
    }

// first-layer variant: K-chunk kb maps wholly to f0 (kb=0,64), f1 (128,192)
// or G (>=256) -> one wave-uniform base select per K-step, branch-free loads.
#define GEMM_LOAD_STAGE64_F(kt)                                                      \
    {                                                                                \
        const int kb = (kt) * GBK64;                                                 \
        if (kb < 256) {                                                              \
            const float* Fs = (kb < 128) ? f0 : f1;                                  \
            const int colOff = kb & 127;                                             \
            const float* Ab0 = Fs + (size_t)(rowBase + ar) * 128 + colOff + ak;      \
            const float* Ab1 = Fs + (size_t)(rowBase + ar + 64) * 128 + colOff + ak; \
            GEMM_A_LOAD64(Ab0, Ab1)                                                  \
            GEMM_W_LOAD64(W1, kb)                                                    \
        } else {                                                                     \
            const int kloc = kb & 255;                                               \
            const float* Ab0 = G + (size_t)(rowBase + ar) * 256 + kloc + ak;         \
            const float* Ab1 = G + (size_t)(rowBase + ar + 64) * 256 + kloc + ak;    \
            GEMM_A_LOAD64(Ab0, Ab1)                                                  \
            GEMM_W_LOAD64(W2, kloc)                                                  \
        }                                                                            \
    }

#define GEMM_STORE_STAGE64()                                                         \
    {                                                                                \
        _Pragma("unroll")                                                            \
        for (int j = 0; j < 4; ++j) {                                                \
            As[ak + j][ar]           = ((const float*)&a_st0)[j];                    \
            As[ak + j][ar + 64]      = ((const float*)&a_st1)[j];                    \
            As[16 + ak + j][ar]      = ((const float*)&a_st2)[j];                    \
            As[16 + ak + j][ar + 64] = ((const float*)&a_st3)[j];                    \
            As[32 + ak + j][ar]      = ((const float*)&a_st4)[j];                    \
            As[32 + ak + j][ar + 64] = ((const float*)&a_st5)[j];                    \
            As[48 + ak + j][ar]      = ((const float*)&a_st6)[j];                    \
            As[48 + ak + j][ar + 64] = ((const float*)&a_st7)[j];                    \
        }                                                                            \
        *(float4*)&Ws[wk][wc]      = w_st0;                                          \
        *(float4*)&Ws[wk + 8][wc]  = w_st1;                                          \
        *(float4*)&Ws[wk + 16][wc] = w_st2;                                          \
        *(float4*)&Ws[wk + 24][wc] = w_st3;                                          \
        *(float4*)&Ws[wk + 32][wc] = w_st4;                                          \
        *(float4*)&Ws[wk + 40][wc] = w_st5;                                          \
        *(float4*)&Ws[wk + 48][wc] = w_st6;                                          \
        *(float4*)&Ws[wk + 56][wc] = w_st7;                                          \
    }

#define GEMM_COMPUTE(BKN)                                                            \
    {                                                                                \
        _Pragma("unroll")                                                            \
        for (int kk = 0; kk < BKN; ++kk) {                                           \
            float a0[4], a1[4], w0[4], w1[4];                                        \
            *(float4*)a0 = *(const float4*)&As[kk][trow * 4];                        \
            *(float4*)a1 = *(const float4*)&As[kk][64 + trow * 4];                   \
            *(float4*)w0 = *(const float4*)&Ws[kk][tcol * 4];                        \
            *(float4*)w1 = *(const float4*)&Ws[kk][64 + tcol * 4];                   \
            _Pragma("unroll")                                                        \
            for (int i = 0; i < 4; ++i)                                              \
                _Pragma("unroll")                                                    \
                for (int j = 0; j < 4; ++j) {                                        \
                    acc[0][i][j] = fmaf(a0[i], w0[j], acc[0][i][j]);                 \
                    acc[1][i][j] = fmaf(a0[i], w1[j], acc[1][i][j]);                 \
                    acc[2][i][j] = fmaf(a1[i], w0[j], acc[2][i][j]);                 \
                    acc[3][i][j] = fmaf(a1[i], w1[j], acc[3][i][j]);                 \
                }                                                                    \
        }                                                                            \
    }

#define GEMM_EPILOGUE()                                                              \
    {                                                                                \
        _Pragma("unroll")                                                            \
        for (int h = 0; h < 2; ++h) {                                                \
            _Pragma("unroll")                                                        \
            for (int i = 0; i < 4; ++i) {                                            \
                const int row = rowBase + h * 64 + trow * 4 + i;                     \
                _Pragma("unroll")                                                    \
                for (int g = 0; g < 2; ++g) {                                        \
                    const int colb = colBase + g * 64 + tcol * 4;                    \
                    float o[4];                                                      \
                    _Pragma("unroll")                                                \
                    for (int j = 0; j < 4; ++j)                                      \
                        o[j] = fmaxf(acc[h * 2 + g][i][j] + bias[colb + j], 0.f);    \
                    *(float4*)(Y + (size_t)row * 256 + colb) = *(const float4*)&o[0];\
                }                                                                    \
            }                                                                        \
        }                                                                            \
    }

#define GEMM_PREAMBLE(BKN)                                                           \
    __shared__ float As[BKN][GBM + 4];                                               \
    __shared__ float Ws[BKN][GBN + 4];                                               \
    const int tid = threadIdx.x;                                                     \
    const int tcol = tid & 15;                                                       \
    const int trow = tid >> 4;                                                       \
    const int rowBase = blockIdx.y * GBM;                                            \
    const int colBase = blockIdx.x * GBN;                                            \
    const int ar = tid >> 2;                                                         \
    const int ak = (tid & 3) * 4;                                                    \
    const int wk = tid >> 5;                                                         \
    const int wc = (tid & 31) * 4;                                                   \
    float acc[4][4][4];                                                              \
    _Pragma("unroll")                                                                \
    for (int q = 0; q < 4; ++q)                                                      \
        _Pragma("unroll")                                                            \
        for (int i = 0; i < 4; ++i)                                                  \
            _Pragma("unroll")                                                        \
            for (int j = 0; j < 4; ++j) acc[q][i][j] = 0.f;

__global__ __launch_bounds__(256) void gemm_two_k64_kernel(
        const float* __restrict__ X, const float* __restrict__ G,
        const float* __restrict__ W1, const float* __restrict__ W2,
        const float* __restrict__ bias, float* __restrict__ Y) {
    GEMM_PREAMBLE(GBK64);
    float4 a_st0, a_st1, a_st2, a_st3, a_st4, a_st5, a_st6, a_st7;
    float4 w_st0, w_st1, w_st2, w_st3, w_st4, w_st5, w_st6, w_st7;
    GEMM_LOAD_STAGE64(0);
    for (int kt = 0; kt < 512 / GBK64; ++kt) {
        __syncthreads();   // previous tile fully consumed
        GEMM_STORE_STAGE64();
        __syncthreads();
        if (kt < 512 / GBK64 - 1) GEMM_LOAD_STAGE64(kt + 1);  // fly under compute
        GEMM_COMPUTE(GBK64);
    }
    GEMM_EPILOGUE();
}

__global__ __launch_bounds__(256) void gemm_first_k64_kernel(
        const float* __restrict__ f0, const float* __restrict__ f1,
        const float* __restrict__ G,
        const float* __restrict__ W1, const float* __restrict__ W2,
        const float* __restrict__ bias, float* __restrict__ Y) {
    GEMM_PREAMBLE(GBK64);
    float4 a_st0, a_st1, a_st2, a_st3, a_st4, a_st5, a_st6, a_st7;
    float4 w_st0, w_st1, w_st2, w_st3, w_st4, w_st5, w_st6, w_st7;
    GEMM_LOAD_STAGE64_F(0);
    for (int kt = 0; kt < 512 / GBK64; ++kt) {
        __syncthreads();
        GEMM_STORE_STAGE64();
        __syncthreads();
        if (kt < 512 / GBK64 - 1) GEMM_LOAD_STAGE64_F(kt + 1);
        GEMM_COMPUTE(GBK64);
    }
    GEMM_EPILOGUE();
}

// ---------------------------------------------------------------------------
// 5a. per-node dots: yr[n] = x3[n].Wpr, yn[n] = x3[n].Wpn   (f64)
// ---------------------------------------------------------------------------
__global__ __launch_bounds__(256) void dot_kernel(const float* __restrict__ X3,
                                                  const float* __restrict__ Wpr,
                                                  const float* __restrict__ Wpn,
                                                  double* __restrict__ yr,
                                                  double* __restrict__ yn, int N) {
    int w = threadIdx.x >> 6;
    int lane = threadIdx.x & 63;
    int n = blockIdx.x * 4 + w;
    if (n >= N) return;
    float4 xv = *(const float4*)(X3 + (size_t)n * 256 + lane * 4);
    float4 wr = *(const float4*)(Wpr + lane * 4);
    float4 wn = *(const float4*)(Wpn + lane * 4);
    double dr = (double)xv.x * wr.x + (double)xv.y * wr.y +
                (double)xv.z * wr.z + (double)xv.w * wr.w;
    double dn = (double)xv.x * wn.x + (double)xv.y * wn.y +
                (double)xv.z * wn.z + (double)xv.w * wn.w;
    #pragma unroll
    for (int o = 32; o > 0; o >>= 1) {
        dr += __shfl_down(dr, o, 64);
        dn += __shfl_down(dn, o, 64);
    }
    if (lane == 0) { yr[n] = dr; yn[n] = dn; }
}

// ---------------------------------------------------------------------------
// 5b. score[n] = yr[n] + sum_{bucket} yn[src] + bp; emit order-preserving key
// ---------------------------------------------------------------------------
__global__ __launch_bounds__(256) void score_gather_kernel(
        const double* __restrict__ yr, const double* __restrict__ yn,
        const int* __restrict__ csr, const int* __restrict__ offs,
        const float* __restrict__ bp,
        double* __restrict__ sc, unsigned long long* __restrict__ keys, int N) {
    int n = blockIdx.x * blockDim.x + threadIdx.x;
    if (n >= N) return;
    double s = yr[n] + (double)bp[0];
    int beg = offs[n], end = offs[n + 1];
    for (int p = beg; p < end; ++p) s += yn[csr[p]];
    sc[n] = s;
    long long sb = __double_as_longlong(s);
    keys[n] = (sb < 0) ? ~(unsigned long long)sb
                       : ((unsigned long long)sb | 0x8000000000000000ULL);
}

// ---------------------------------------------------------------------------
// 6a. tiled exact rank-count on uint64 keys.
// ---------------------------------------------------------------------------
#define RTI 1024
#define RTJ 512
__global__ __launch_bounds__(256) void rank_count_kernel(
        const unsigned long long* __restrict__ keys,
        int* __restrict__ rankcnt, int N) {
    __shared__ __align__(16) unsigned long long sk[RTJ];
    const int tid = threadIdx.x;
    const int ibase = blockIdx.y * RTI;
    const int jbase = blockIdx.x * RTJ;

    unsigned long long ki[4];
    #pragma unroll
    for (int r = 0; r < 4; ++r) ki[r] = keys[ibase + r * 256 + tid];
    for (int t = tid; t < RTJ; t += 256) sk[t] = keys[jbase + t];
    __syncthreads();

    int cnt[4] = {0, 0, 0, 0};
    if (jbase + RTJ <= ibase) {
        for (int u = 0; u < RTJ; u += 8) {
            ulonglong2 p0 = *(const ulonglong2*)&sk[u];
            ulonglong2 p1 = *(const ulonglong2*)&sk[u + 2];
            ulonglong2 p2 = *(const ulonglong2*)&sk[u + 4];
            ulonglong2 p3 = *(const ulonglong2*)&sk[u + 6];
            #pragma unroll
            for (int r = 0; r < 4; ++r) {
                cnt[r] += (int)(p0.x >= ki[r]) + (int)(p0.y >= ki[r])
                        + (int)(p1.x >= ki[r]) + (int)(p1.y >= ki[r])
                        + (int)(p2.x >= ki[r]) + (int)(p2.y >= ki[r])
                        + (int)(p3.x >= ki[r]) + (int)(p3.y >= ki[r]);
            }
        }
    } else if (jbase >= ibase + RTI) {
        for (int u = 0; u < RTJ; u += 8) {
            ulonglong2 p0 = *(const ulonglong2*)&sk[u];
            ulonglong2 p1 = *(const ulonglong2*)&sk[u + 2];
            ulonglong2 p2 = *(const ulonglong2*)&sk[u + 4];
            ulonglong2 p3 = *(const ulonglong2*)&sk[u + 6];
            #pragma unroll
            for (int r = 0; r < 4; ++r) {
                cnt[r] += (int)(p0.x > ki[r]) + (int)(p0.y > ki[r])
                        + (int)(p1.x > ki[r]) + (int)(p1.y > ki[r])
                        + (int)(p2.x > ki[r]) + (int)(p2.y > ki[r])
                        + (int)(p3.x > ki[r]) + (int)(p3.y > ki[r]);
            }
        }
    } else {
        int thr[4];
        #pragma unroll
        for (int r = 0; r < 4; ++r) thr[r] = ibase + r * 256 + tid - jbase;
        for (int u = 0; u < RTJ; ++u) {
            unsigned long long kj = sk[u];
            #pragma unroll
            for (int r = 0; r < 4; ++r)
                cnt[r] += (kj > ki[r]) || (kj == ki[r] && u < thr[r]);
        }
    }
    #pragma unroll
    for (int r = 0; r < 4; ++r)
        atomicAdd(&rankcnt[ibase + r * 256 + tid], cnt[r]);
}

// ---------------------------------------------------------------------------
// 6b. scatter by rank
// ---------------------------------------------------------------------------
__global__ __launch_bounds__(256) void rank_scatter_kernel(
        const int* __restrict__ rankcnt,
        const double* __restrict__ sc,
        int* __restrict__ perm,
        double* __restrict__ topd, int N, int K) {
    int i = blockIdx.x * blockDim.x + threadIdx.x;
    if (i >= N) return;
    int rank = rankcnt[i];
    if (rank < K) { perm[rank] = i; topd[rank] = sc[i]; }
}

// ---------------------------------------------------------------------------
// 7. head: out[r] = relu(x3[perm[r]] * tanh(score_r)) @ Wc + bc  (f64 accum)
// ---------------------------------------------------------------------------
__global__ __launch_bounds__(256) void out_kernel(const float* __restrict__ X3,
                                                  const int* __restrict__ perm,
                                                  const double* __restrict__ topd,
                                                  const float* __restrict__ Wc,
                                                  const float* __restrict__ bc,
                                                  float* __restrict__ out, int K) {
    int w = threadIdx.x >> 6;
    int lane = threadIdx.x & 63;
    int r = blockIdx.x * 4 + w;
    if (r >= K) return;
    int p = perm[r];
    double t = tanh(topd[r]);
    float4 xv = *(const float4*)(X3 + (size_t)p * 256 + lane * 4);
    double xp[4];
    xp[0] = (double)xv.x * t; xp[1] = (double)xv.y * t;
    xp[2] = (double)xv.z * t; xp[3] = (double)xv.w * t;
    #pragma unroll
    for (int j = 0; j < 4; ++j) xp[j] = xp[j] > 0.0 ? xp[j] : 0.0;
    double acc[11];
    #pragma unroll
    for (int c = 0; c < 11; ++c) acc[c] = 0.0;
    #pragma unroll
    for (int j = 0; j < 4; ++j) {
        const float* wrow = Wc + (size_t)(lane * 4 + j) * 11;
        #pragma unroll
        for (int c = 0; c < 11; ++c) acc[c] += xp[j] * (double)wrow[c];
    }
    #pragma unroll
    for (int c = 0; c < 11; ++c) {
        double v = acc[c];
        #pragma unroll
        for (int o = 32; o > 0; o >>= 1) v += __shfl_down(v, o, 64);
        if (lane == 0) out[(size_t)r * 11 + c] = (float)(v + (double)bc[c]);
    }
}

// ---------------------------------------------------------------------------
// launch
// ---------------------------------------------------------------------------
extern "C" void kernel_launch(void* const* d_in, const int* in_sizes, int n_in,
                              void* d_out, int out_size, void* d_ws, size_t ws_size,
                              hipStream_t stream) {
    const float* f0  = (const float*)d_in[0];
    const float* f1  = (const float*)d_in[1];
    const int*   ei  = (const int*)d_in[2];
    const float* Wr  = (const float*)d_in[3];
    const float* Wn  = (const float*)d_in[4];
    const float* b   = (const float*)d_in[5];
    const float* Wpr = (const float*)d_in[6];
    const float* Wpn = (const float*)d_in[7];
    const float* bp  = (const float*)d_in[8];
    const float* Wc  = (const float*)d_in[9];
    const float* bc  = (const float*)d_in[10];
    float* out = (float*)d_out;

    const int N = in_sizes[0] / 128;   // 32768
    const int E = in_sizes[2] / 2;     // 524288
    const int K = (N + 1) / 2;         // 16384

    const int* src = ei;
    const int* dst = ei + E;

    // workspace layout (256B aligned slices)
    char* p = (char*)d_ws;
    auto take = [&](size_t bytes) {
        char* r = p;
        p += (bytes + 255) & ~(size_t)255;
        return r;
    };
    float*  xA      = (float*)take((size_t)N * 256 * 4);
    float*  xB      = (float*)take((size_t)N * 256 * 4);
    float*  agg     = (float*)take((size_t)N * 256 * 4);
    int*    counts  = (int*)take((size_t)N * 4);
    int*    offs    = (int*)take((size_t)(N + 1) * 4);
    int*    csr     = (int*)take((size_t)E * 4);
    double* sc      = (double*)take((size_t)N * 8);
    unsigned long long* keys = (unsigned long long*)take((size_t)N * 8);
    int*    rankcnt = (int*)take((size_t)N * 4);
    double* topd    = (double*)take((size_t)K * 8);
    int*    perm    = (int*)take((size_t)K * 4);
    double* yrv     = (double*)take((size_t)N * 8);
    double* ynv     = (double*)take((size_t)N * 8);
    (void)ws_size;

    hipMemsetAsync(counts, 0, (size_t)N * 4, stream);
    hipMemsetAsync(rankcnt, 0, (size_t)N * 4, stream);

    count_kernel<<<(E + 255) / 256, 256, 0, stream>>>(dst, counts, E);
    scan_kernel<<<1, 1024, 0, stream>>>(counts, offs, N, E);
    fill_kernel<<<(E + 255) / 256, 256, 0, stream>>>(dst, offs, counts, csr, E);
    bsort_kernel<<<(N + 255) / 256, 256, 0, stream>>>(csr, offs, src, N);

    // layer 0: virtual-concat inputs (no materialized x0), BK=64
    segsum_first_kernel<<<N / 4, 256, 0, stream>>>(f0, f1, csr, offs, agg, N);
    gemm_first_k64_kernel<<<dim3(256 / GBN, N / GBM), 256, 0, stream>>>(
        f0, f1, agg, Wr, Wn, b, xB);

    // layer 1: BK=64
    segsum_kernel<<<N / 4, 256, 0, stream>>>(xB, csr, offs, agg, N);
    gemm_two_k64_kernel<<<dim3(256 / GBN, N / GBM), 256, 0, stream>>>(
        xB, agg, Wr + 65536, Wn + 65536, b + 256, xA);

    // layer 2: BK=64
    segsum_kernel<<<N / 4, 256, 0, stream>>>(xA, csr, offs, agg, N);
    gemm_two_k64_kernel<<<dim3(256 / GBN, N / GBM), 256, 0, stream>>>(
        xA, agg, Wr + 2 * 65536, Wn + 2 * 65536, b + 2 * 256, xB);

    float* xcur = xB;  // x3
    dot_kernel<<<N / 4, 256, 0, stream>>>(xcur, Wpr, Wpn, yrv, ynv, N);
    score_gather_kernel<<<N / 256, 256, 0, stream>>>(yrv, ynv, csr, offs, bp, sc, keys, N);
    rank_count_kernel<<<dim3(N / RTJ, N / RTI), 256, 0, stream>>>(keys, rankcnt, N);
    rank_scatter_kernel<<<(N + 255) / 256, 256, 0, stream>>>(rankcnt, sc, perm, topd, N, K);
    out_kernel<<<K / 4, 256, 0, stream>>>(xcur, perm, topd, Wc, bc, out, K);
}

// Round 13
// 782.965 us; speedup vs baseline: 2.1413x; 1.0072x over previous
//
#include <hip/hip_runtime.h>
#include <hip/hip_bf16.h>
#include <math.h>
#include <stdint.h>

// N = 32768 nodes, D = 256 features, E = 524288 edges, L = 3 layers,
// K = 16384 (top-k), C = 11 classes.
// GEMM history (per-layer dispatch time):
//   BK=32 4x(4x4) fused, 124-128 VGPR ........ 127 us
//   __launch_bounds__(256,4) clamp ........... spill, 1.2GB/dispatch (r5)
//   16x8 microtile ........................... 200 VGPR, 11% occ, 169 us (r7)
//   LDS double-buffer ........................ 256 VGPR, spill, 420+ us (r8)
//   BK=64 single-buffer ...................... 114.7 us, 92 VGPR  <- FINAL
// r13: segsum 4-way ILP (batch idx load + 4 independent row loads) to break
// the idx->row serial chain; segsum estimated ~80us each (latency signature).

// ---------------------------------------------------------------------------
// 2a. histogram of dst
// ---------------------------------------------------------------------------
__global__ __launch_bounds__(256) void count_kernel(const int* __restrict__ dst,
                                                    int* __restrict__ counts, int E) {
    int e = blockIdx.x * blockDim.x + threadIdx.x;
    if (e < E) atomicAdd(&counts[dst[e]], 1);
}

// ---------------------------------------------------------------------------
// 2b. exclusive scan of counts -> offsets[N+1]; zero counts (reused as cursor)
// ---------------------------------------------------------------------------
__global__ __launch_bounds__(1024) void scan_kernel(int* __restrict__ counts,
                                                    int* __restrict__ offs,
                                                    int N, int E) {
    __shared__ int s[1024];
    int t = threadIdx.x;
    int base = t * 32;
    int local[32];
    int sum = 0;
    #pragma unroll
    for (int j = 0; j < 32; ++j) { local[j] = counts[base + j]; sum += local[j]; }
    s[t] = sum;
    __syncthreads();
    for (int off = 1; off < 1024; off <<= 1) {
        int other = (t >= off) ? s[t - off] : 0;
        __syncthreads();
        s[t] += other;
        __syncthreads();
    }
    int run = s[t] - sum;  // exclusive base for this thread
    #pragma unroll
    for (int j = 0; j < 32; ++j) {
        offs[base + j] = run;
        run += local[j];
        counts[base + j] = 0;   // reset: reused as cursor in fill_kernel
    }
    if (t == 1023) offs[N] = E;
}

// ---------------------------------------------------------------------------
// 2c. scatter edge ids into CSR buckets
// ---------------------------------------------------------------------------
__global__ __launch_bounds__(256) void fill_kernel(const int* __restrict__ dst,
                                                   const int* __restrict__ offs,
                                                   int* __restrict__ cursor,
                                                   int* __restrict__ csr, int E) {
    int e = blockIdx.x * blockDim.x + threadIdx.x;
    if (e >= E) return;
    int d = dst[e];
    int pos = offs[d] + atomicAdd(&cursor[d], 1);
    csr[pos] = e;
}

// ---------------------------------------------------------------------------
// 2d. per-bucket insertion sort by edge id (deterministic), map edge->src
// ---------------------------------------------------------------------------
__global__ __launch_bounds__(256) void bsort_kernel(int* __restrict__ csr,
                                                    const int* __restrict__ offs,
                                                    const int* __restrict__ src,
                                                    int N) {
    int i = blockIdx.x * blockDim.x + threadIdx.x;
    if (i >= N) return;
    int beg = offs[i], end = offs[i + 1];
    for (int a = beg + 1; a < end; ++a) {
        int v = csr[a];
        int b = a - 1;
        while (b >= beg && csr[b] > v) { csr[b + 1] = csr[b]; --b; }
        csr[b + 1] = v;
    }
    for (int p = beg; p < end; ++p) csr[p] = src[csr[p]];
}

// ---------------------------------------------------------------------------
// 3. segment sum with 4-way ILP: agg[n][:] = sum over csr bucket of x[src][:]
//    4 indices batched -> 4 independent row loads in flight per iteration.
// ---------------------------------------------------------------------------
__global__ __launch_bounds__(256) void segsum_kernel(const float* __restrict__ X,
                                                     const int* __restrict__ csr,
                                                     const int* __restrict__ offs,
                                                     float* __restrict__ AGG, int N) {
    int w = threadIdx.x >> 6;
    int lane = threadIdx.x & 63;
    int n = blockIdx.x * 4 + w;
    if (n >= N) return;
    int beg = offs[n], end = offs[n + 1];
    float4 acc = make_float4(0.f, 0.f, 0.f, 0.f);
    const float* Xl = X + lane * 4;
    int p = beg;
    for (; p + 4 <= end; p += 4) {
        int s0 = csr[p], s1 = csr[p + 1], s2 = csr[p + 2], s3 = csr[p + 3];
        float4 v0 = *(const float4*)(Xl + (size_t)s0 * 256);
        float4 v1 = *(const float4*)(Xl + (size_t)s1 * 256);
        float4 v2 = *(const float4*)(Xl + (size_t)s2 * 256);
        float4 v3 = *(const float4*)(Xl + (size_t)s3 * 256);
        acc.x += v0.x; acc.y += v0.y; acc.z += v0.z; acc.w += v0.w;
        acc.x += v1.x; acc.y += v1.y; acc.z += v1.z; acc.w += v1.w;
        acc.x += v2.x; acc.y += v2.y; acc.z += v2.z; acc.w += v2.w;
        acc.x += v3.x; acc.y += v3.y; acc.z += v3.z; acc.w += v3.w;
    }
    for (; p < end; ++p) {
        int s = csr[p];
        float4 v = *(const float4*)(Xl + (size_t)s * 256);
        acc.x += v.x; acc.y += v.y; acc.z += v.z; acc.w += v.w;
    }
    *(float4*)(AGG + (size_t)n * 256 + lane * 4) = acc;
}

// ---------------------------------------------------------------------------
// 3f. first-layer segment sum (virtual concat) with 4-way ILP.
// ---------------------------------------------------------------------------
__global__ __launch_bounds__(256) void segsum_first_kernel(
        const float* __restrict__ f0, const float* __restrict__ f1,
        const int* __restrict__ csr, const int* __restrict__ offs,
        float* __restrict__ AGG, int N) {
    int w = threadIdx.x >> 6;
    int lane = threadIdx.x & 63;
    int n = blockIdx.x * 4 + w;
    if (n >= N) return;
    const float* base = (lane < 32) ? (f0 + lane * 4) : (f1 + (lane - 32) * 4);
    int beg = offs[n], end = offs[n + 1];
    float4 acc = make_float4(0.f, 0.f, 0.f, 0.f);
    int p = beg;
    for (; p + 4 <= end; p += 4) {
        int s0 = csr[p], s1 = csr[p + 1], s2 = csr[p + 2], s3 = csr[p + 3];
        float4 v0 = *(const float4*)(base + (size_t)s0 * 128);
        float4 v1 = *(const float4*)(base + (size_t)s1 * 128);
        float4 v2 = *(const float4*)(base + (size_t)s2 * 128);
        float4 v3 = *(const float4*)(base + (size_t)s3 * 128);
        acc.x += v0.x; acc.y += v0.y; acc.z += v0.z; acc.w += v0.w;
        acc.x += v1.x; acc.y += v1.y; acc.z += v1.z; acc.w += v1.w;
        acc.x += v2.x; acc.y += v2.y; acc.z += v2.z; acc.w += v2.w;
        acc.x += v3.x; acc.y += v3.y; acc.z += v3.z; acc.w += v3.w;
    }
    for (; p < end; ++p) {
        int s = csr[p];
        float4 v = *(const float4*)(base + (size_t)s * 128);
        acc.x += v.x; acc.y += v.y; acc.z += v.z; acc.w += v.w;
    }
    *(float4*)(AGG + (size_t)n * 256 + lane * 4) = acc;
}

// ---------------------------------------------------------------------------
// 4. fused GEMM: Y = relu(X @ W1 + G @ W2 + bias)   [N,512-split] x [512,256]
//    128x128 tile, BK=64, 256 threads, 4x(4x4) quadrant micro-tile,
//    single LDS buffer, 8 barrier pairs per block.
// ---------------------------------------------------------------------------
#define GBM 128
#define GBN 128
#define GBK64 64

#define GEMM_W_LOAD64(Wsrc, kloc)                                                    \
    {                                                                                \
        const float* Wb = (Wsrc) + (size_t)((kloc) + wk) * 256 + colBase + wc;       \
        w_st0 = *(const float4*)(Wb);                                                \
        w_st1 = *(const float4*)(Wb + 8 * 256);                                      \
        w_st2 = *(const float4*)(Wb + 16 * 256);                                     \
        w_st3 = *(const float4*)(Wb + 24 * 256);                                     \
        w_st4 = *(const float4*)(Wb + 32 * 256);                                     \
        w_st5 = *(const float4*)(Wb + 40 * 256);                                     \
        w_st6 = *(const float4*)(Wb + 48 * 256);                                     \
        w_st7 = *(const float4*)(Wb + 56 * 256);                                     \
    }

#define GEMM_A_LOAD64(Ab0, Ab1)                                                      \
    {                                                                                \
        a_st0 = *(const float4*)(Ab0);                                               \
        a_st1 = *(const float4*)(Ab1);                                               \
        a_st2 = *(const float4*)((Ab0) + 16);                                        \
        a_st3 = *(const float4*)((Ab1) + 16);                                        \
        a_st4 = *(const float4*)((Ab0) + 32);                                        \
        a_st5 = *(const float4*)((Ab1) + 32);                                        \
        a_st6 = *(const float4*)((Ab0) + 48);                                        \
        a_st7 = *(const float4*)((Ab1) + 48);                                        \
    }

#define GEMM_LOAD_STAGE64(kt)                                                        \
    {                                                                                \
        const int kb = (kt) * GBK64;                                                 \
        const float* Asrc = (kb < 256) ? X : G;                                      \
        const float* Wsrc = (kb < 256) ? W1 : W2;                                    \
        const int kloc = kb & 255;                                                   \
        const float* Ab0 = Asrc + (size_t)(rowBase + ar) * 256 + kloc + ak;          \
        const float* Ab1 = Asrc + (size_t)(rowBase + ar + 64) * 256 + kloc + ak;     \
        GEMM_A_LOAD64(Ab0, Ab1)                                                      \
        GEMM_W_LOAD64(Wsrc, kloc)                                                    \
    }

// first-layer variant: K-chunk kb maps wholly to f0 (kb=0,64), f1 (128,192)
// or G (>=256) -> one wave-uniform base select per K-step, branch-free loads.
#define GEMM_LOAD_STAGE64_F(kt)                                                      \
    {                                                                                \
        const int kb = (kt) * GBK64;                                                 \
        if (kb < 256) {                                                              \
            const float* Fs = (kb < 128) ? f0 : f1;                                  \
            const int colOff = kb & 127;                                             \
            const float* Ab0 = Fs + (size_t)(rowBase + ar) * 128 + colOff + ak;      \
            const float* Ab1 = Fs + (size_t)(rowBase + ar + 64) * 128 + colOff + ak; \
            GEMM_A_LOAD64(Ab0, Ab1)                                                  \
            GEMM_W_LOAD64(W1, kb)                                                    \
        } else {                                                                     \
            const int kloc = kb & 255;                                               \
            const float* Ab0 = G + (size_t)(rowBase + ar) * 256 + kloc + ak;         \
            const float* Ab1 = G + (size_t)(rowBase + ar + 64) * 256 + kloc + ak;    \
            GEMM_A_LOAD64(Ab0, Ab1)                                                  \
            GEMM_W_LOAD64(W2, kloc)                                                  \
        }                                                                            \
    }

#define GEMM_STORE_STAGE64()                                                         \
    {                                                                                \
        _Pragma("unroll")                                                            \
        for (int j = 0; j < 4; ++j) {                                                \
            As[ak + j][ar]           = ((const float*)&a_st0)[j];                    \
            As[ak + j][ar + 64]      = ((const float*)&a_st1)[j];                    \
            As[16 + ak + j][ar]      = ((const float*)&a_st2)[j];                    \
            As[16 + ak + j][ar + 64] = ((const float*)&a_st3)[j];                    \
            As[32 + ak + j][ar]      = ((const float*)&a_st4)[j];                    \
            As[32 + ak + j][ar + 64] = ((const float*)&a_st5)[j];                    \
            As[48 + ak + j][ar]      = ((const float*)&a_st6)[j];                    \
            As[48 + ak + j][ar + 64] = ((const float*)&a_st7)[j];                    \
        }                                                                            \
        *(float4*)&Ws[wk][wc]      = w_st0;                                          \
        *(float4*)&Ws[wk + 8][wc]  = w_st1;                                          \
        *(float4*)&Ws[wk + 16][wc] = w_st2;                                          \
        *(float4*)&Ws[wk + 24][wc] = w_st3;                                          \
        *(float4*)&Ws[wk + 32][wc] = w_st4;                                          \
        *(float4*)&Ws[wk + 40][wc] = w_st5;                                          \
        *(float4*)&Ws[wk + 48][wc] = w_st6;                                          \
        *(float4*)&Ws[wk + 56][wc] = w_st7;                                          \
    }

#define GEMM_COMPUTE(BKN)                                                            \
    {                                                                                \
        _Pragma("unroll")                                                            \
        for (int kk = 0; kk < BKN; ++kk) {                                           \
            float a0[4], a1[4], w0[4], w1[4];                                        \
            *(float4*)a0 = *(const float4*)&As[kk][trow * 4];                        \
            *(float4*)a1 = *(const float4*)&As[kk][64 + trow * 4];                   \
            *(float4*)w0 = *(const float4*)&Ws[kk][tcol * 4];                        \
            *(float4*)w1 = *(const float4*)&Ws[kk][64 + tcol * 4];                   \
            _Pragma("unroll")                                                        \
            for (int i = 0; i < 4; ++i)                                              \
                _Pragma("unroll")                                                    \
                for (int j = 0; j < 4; ++j) {                                        \
                    acc[0][i][j] = fmaf(a0[i], w0[j], acc[0][i][j]);                 \
                    acc[1][i][j] = fmaf(a0[i], w1[j], acc[1][i][j]);                 \
                    acc[2][i][j] = fmaf(a1[i], w0[j], acc[2][i][j]);                 \
                    acc[3][i][j] = fmaf(a1[i], w1[j], acc[3][i][j]);                 \
                }                                                                    \
        }                                                                            \
    }

#define GEMM_EPILOGUE()                                                              \
    {                                                                                \
        _Pragma("unroll")                                                            \
        for (int h = 0; h < 2; ++h) {                                                \
            _Pragma("unroll")                                                        \
            for (int i = 0; i < 4; ++i) {                                            \
                const int row = rowBase + h * 64 + trow * 4 + i;                     \
                _Pragma("unroll")                                                    \
                for (int g = 0; g < 2; ++g) {                                        \
                    const int colb = colBase + g * 64 + tcol * 4;                    \
                    float o[4];                                                      \
                    _Pragma("unroll")                                                \
                    for (int j = 0; j < 4; ++j)                                      \
                        o[j] = fmaxf(acc[h * 2 + g][i][j] + bias[colb + j], 0.f);    \
                    *(float4*)(Y + (size_t)row * 256 + colb) = *(const float4*)&o[0];\
                }                                                                    \
            }                                                                        \
        }                                                                            \
    }

#define GEMM_PREAMBLE(BKN)                                                           \
    __shared__ float As[BKN][GBM + 4];                                               \
    __shared__ float Ws[BKN][GBN + 4];                                               \
    const int tid = threadIdx.x;                                                     \
    const int tcol = tid & 15;                                                       \
    const int trow = tid >> 4;                                                       \
    const int rowBase = blockIdx.y * GBM;                                            \
    const int colBase = blockIdx.x * GBN;                                            \
    const int ar = tid >> 2;                                                         \
    const int ak = (tid & 3) * 4;                                                    \
    const int wk = tid >> 5;                                                         \
    const int wc = (tid & 31) * 4;                                                   \
    float acc[4][4][4];                                                              \
    _Pragma("unroll")                                                                \
    for (int q = 0; q < 4; ++q)                                                      \
        _Pragma("unroll")                                                            \
        for (int i = 0; i < 4; ++i)                                                  \
            _Pragma("unroll")                                                        \
            for (int j = 0; j < 4; ++j) acc[q][i][j] = 0.f;

__global__ __launch_bounds__(256) void gemm_two_k64_kernel(
        const float* __restrict__ X, const float* __restrict__ G,
        const float* __restrict__ W1, const float* __restrict__ W2,
        const float* __restrict__ bias, float* __restrict__ Y) {
    GEMM_PREAMBLE(GBK64);
    float4 a_st0, a_st1, a_st2, a_st3, a_st4, a_st5, a_st6, a_st7;
    float4 w_st0, w_st1, w_st2, w_st3, w_st4, w_st5, w_st6, w_st7;
    GEMM_LOAD_STAGE64(0);
    for (int kt = 0; kt < 512 / GBK64; ++kt) {
        __syncthreads();   // previous tile fully consumed
        GEMM_STORE_STAGE64();
        __syncthreads();
        if (kt < 512 / GBK64 - 1) GEMM_LOAD_STAGE64(kt + 1);  // fly under compute
        GEMM_COMPUTE(GBK64);
    }
    GEMM_EPILOGUE();
}

__global__ __launch_bounds__(256) void gemm_first_k64_kernel(
        const float* __restrict__ f0, const float* __restrict__ f1,
        const float* __restrict__ G,
        const float* __restrict__ W1, const float* __restrict__ W2,
        const float* __restrict__ bias, float* __restrict__ Y) {
    GEMM_PREAMBLE(GBK64);
    float4 a_st0, a_st1, a_st2, a_st3, a_st4, a_st5, a_st6, a_st7;
    float4 w_st0, w_st1, w_st2, w_st3, w_st4, w_st5, w_st6, w_st7;
    GEMM_LOAD_STAGE64_F(0);
    for (int kt = 0; kt < 512 / GBK64; ++kt) {
        __syncthreads();
        GEMM_STORE_STAGE64();
        __syncthreads();
        if (kt < 512 / GBK64 - 1) GEMM_LOAD_STAGE64_F(kt + 1);
        GEMM_COMPUTE(GBK64);
    }
    GEMM_EPILOGUE();
}

// ---------------------------------------------------------------------------
// 5a. per-node dots: yr[n] = x3[n].Wpr, yn[n] = x3[n].Wpn   (f64)
// ---------------------------------------------------------------------------
__global__ __launch_bounds__(256) void dot_kernel(const float* __restrict__ X3,
                                                  const float* __restrict__ Wpr,
                                                  const float* __restrict__ Wpn,
                                                  double* __restrict__ yr,
                                                  double* __restrict__ yn, int N) {
    int w = threadIdx.x >> 6;
    int lane = threadIdx.x & 63;
    int n = blockIdx.x * 4 + w;
    if (n >= N) return;
    float4 xv = *(const float4*)(X3 + (size_t)n * 256 + lane * 4);
    float4 wr = *(const float4*)(Wpr + lane * 4);
    float4 wn = *(const float4*)(Wpn + lane * 4);
    double dr = (double)xv.x * wr.x + (double)xv.y * wr.y +
                (double)xv.z * wr.z + (double)xv.w * wr.w;
    double dn = (double)xv.x * wn.x + (double)xv.y * wn.y +
                (double)xv.z * wn.z + (double)xv.w * wn.w;
    #pragma unroll
    for (int o = 32; o > 0; o >>= 1) {
        dr += __shfl_down(dr, o, 64);
        dn += __shfl_down(dn, o, 64);
    }
    if (lane == 0) { yr[n] = dr; yn[n] = dn; }
}

// ---------------------------------------------------------------------------
// 5b. score[n] = yr[n] + sum_{bucket} yn[src] + bp; emit order-preserving key
// ---------------------------------------------------------------------------
__global__ __launch_bounds__(256) void score_gather_kernel(
        const double* __restrict__ yr, const double* __restrict__ yn,
        const int* __restrict__ csr, const int* __restrict__ offs,
        const float* __restrict__ bp,
        double* __restrict__ sc, unsigned long long* __restrict__ keys, int N) {
    int n = blockIdx.x * blockDim.x + threadIdx.x;
    if (n >= N) return;
    double s = yr[n] + (double)bp[0];
    int beg = offs[n], end = offs[n + 1];
    for (int p = beg; p < end; ++p) s += yn[csr[p]];
    sc[n] = s;
    long long sb = __double_as_longlong(s);
    keys[n] = (sb < 0) ? ~(unsigned long long)sb
                       : ((unsigned long long)sb | 0x8000000000000000ULL);
}

// ---------------------------------------------------------------------------
// 6a. tiled exact rank-count on uint64 keys.
// ---------------------------------------------------------------------------
#define RTI 1024
#define RTJ 512
__global__ __launch_bounds__(256) void rank_count_kernel(
        const unsigned long long* __restrict__ keys,
        int* __restrict__ rankcnt, int N) {
    __shared__ __align__(16) unsigned long long sk[RTJ];
    const int tid = threadIdx.x;
    const int ibase = blockIdx.y * RTI;
    const int jbase = blockIdx.x * RTJ;

    unsigned long long ki[4];
    #pragma unroll
    for (int r = 0; r < 4; ++r) ki[r] = keys[ibase + r * 256 + tid];
    for (int t = tid; t < RTJ; t += 256) sk[t] = keys[jbase + t];
    __syncthreads();

    int cnt[4] = {0, 0, 0, 0};
    if (jbase + RTJ <= ibase) {
        for (int u = 0; u < RTJ; u += 8) {
            ulonglong2 p0 = *(const ulonglong2*)&sk[u];
            ulonglong2 p1 = *(const ulonglong2*)&sk[u + 2];
            ulonglong2 p2 = *(const ulonglong2*)&sk[u + 4];
            ulonglong2 p3 = *(const ulonglong2*)&sk[u + 6];
            #pragma unroll
            for (int r = 0; r < 4; ++r) {
                cnt[r] += (int)(p0.x >= ki[r]) + (int)(p0.y >= ki[r])
                        + (int)(p1.x >= ki[r]) + (int)(p1.y >= ki[r])
                        + (int)(p2.x >= ki[r]) + (int)(p2.y >= ki[r])
                        + (int)(p3.x >= ki[r]) + (int)(p3.y >= ki[r]);
            }
        }
    } else if (jbase >= ibase + RTI) {
        for (int u = 0; u < RTJ; u += 8) {
            ulonglong2 p0 = *(const ulonglong2*)&sk[u];
            ulonglong2 p1 = *(const ulonglong2*)&sk[u + 2];
            ulonglong2 p2 = *(const ulonglong2*)&sk[u + 4];
            ulonglong2 p3 = *(const ulonglong2*)&sk[u + 6];
            #pragma unroll
            for (int r = 0; r < 4; ++r) {
                cnt[r] += (int)(p0.x > ki[r]) + (int)(p0.y > ki[r])
                        + (int)(p1.x > ki[r]) + (int)(p1.y > ki[r])
                        + (int)(p2.x > ki[r]) + (int)(p2.y > ki[r])
                        + (int)(p3.x > ki[r]) + (int)(p3.y > ki[r]);
            }
        }
    } else {
        int thr[4];
        #pragma unroll
        for (int r = 0; r < 4; ++r) thr[r] = ibase + r * 256 + tid - jbase;
        for (int u = 0; u < RTJ; ++u) {
            unsigned long long kj = sk[u];
            #pragma unroll
            for (int r = 0; r < 4; ++r)
                cnt[r] += (kj > ki[r]) || (kj == ki[r] && u < thr[r]);
        }
    }
    #pragma unroll
    for (int r = 0; r < 4; ++r)
        atomicAdd(&rankcnt[ibase + r * 256 + tid], cnt[r]);
}

// ---------------------------------------------------------------------------
// 6b. scatter by rank
// ---------------------------------------------------------------------------
__global__ __launch_bounds__(256) void rank_scatter_kernel(
        const int* __restrict__ rankcnt,
        const double* __restrict__ sc,
        int* __restrict__ perm,
        double* __restrict__ topd, int N, int K) {
    int i = blockIdx.x * blockDim.x + threadIdx.x;
    if (i >= N) return;
    int rank = rankcnt[i];
    if (rank < K) { perm[rank] = i; topd[rank] = sc[i]; }
}

// ---------------------------------------------------------------------------
// 7. head: out[r] = relu(x3[perm[r]] * tanh(score_r)) @ Wc + bc  (f64 accum)
// ---------------------------------------------------------------------------
__global__ __launch_bounds__(256) void out_kernel(const float* __restrict__ X3,
                                                  const int* __restrict__ perm,
                                                  const double* __restrict__ topd,
                                                  const float* __restrict__ Wc,
                                                  const float* __restrict__ bc,
                                                  float* __restrict__ out, int K) {
    int w = threadIdx.x >> 6;
    int lane = threadIdx.x & 63;
    int r = blockIdx.x * 4 + w;
    if (r >= K) return;
    int p = perm[r];
    double t = tanh(topd[r]);
    float4 xv = *(const float4*)(X3 + (size_t)p * 256 + lane * 4);
    double xp[4];
    xp[0] = (double)xv.x * t; xp[1] = (double)xv.y * t;
    xp[2] = (double)xv.z * t; xp[3] = (double)xv.w * t;
    #pragma unroll
    for (int j = 0; j < 4; ++j) xp[j] = xp[j] > 0.0 ? xp[j] : 0.0;
    double acc[11];
    #pragma unroll
    for (int c = 0; c < 11; ++c) acc[c] = 0.0;
    #pragma unroll
    for (int j = 0; j < 4; ++j) {
        const float* wrow = Wc + (size_t)(lane * 4 + j) * 11;
        #pragma unroll
        for (int c = 0; c < 11; ++c) acc[c] += xp[j] * (double)wrow[c];
    }
    #pragma unroll
    for (int c = 0; c < 11; ++c) {
        double v = acc[c];
        #pragma unroll
        for (int o = 32; o > 0; o >>= 1) v += __shfl_down(v, o, 64);
        if (lane == 0) out[(size_t)r * 11 + c] = (float)(v + (double)bc[c]);
    }
}

// ---------------------------------------------------------------------------
// launch
// ---------------------------------------------------------------------------
extern "C" void kernel_launch(void* const* d_in, const int* in_sizes, int n_in,
                              void* d_out, int out_size, void* d_ws, size_t ws_size,
                              hipStream_t stream) {
    const float* f0  = (const float*)d_in[0];
    const float* f1  = (const float*)d_in[1];
    const int*   ei  = (const int*)d_in[2];
    const float* Wr  = (const float*)d_in[3];
    const float* Wn  = (const float*)d_in[4];
    const float* b   = (const float*)d_in[5];
    const float* Wpr = (const float*)d_in[6];
    const float* Wpn = (const float*)d_in[7];
    const float* bp  = (const float*)d_in[8];
    const float* Wc  = (const float*)d_in[9];
    const float* bc  = (const float*)d_in[10];
    float* out = (float*)d_out;

    const int N = in_sizes[0] / 128;   // 32768
    const int E = in_sizes[2] / 2;     // 524288
    const int K = (N + 1) / 2;         // 16384

    const int* src = ei;
    const int* dst = ei + E;

    // workspace layout (256B aligned slices)
    char* p = (char*)d_ws;
    auto take = [&](size_t bytes) {
        char* r = p;
        p += (bytes + 255) & ~(size_t)255;
        return r;
    };
    float*  xA      = (float*)take((size_t)N * 256 * 4);
    float*  xB      = (float*)take((size_t)N * 256 * 4);
    float*  agg     = (float*)take((size_t)N * 256 * 4);
    int*    counts  = (int*)take((size_t)N * 4);
    int*    offs    = (int*)take((size_t)(N + 1) * 4);
    int*    csr     = (int*)take((size_t)E * 4);
    double* sc      = (double*)take((size_t)N * 8);
    unsigned long long* keys = (unsigned long long*)take((size_t)N * 8);
    int*    rankcnt = (int*)take((size_t)N * 4);
    double* topd    = (double*)take((size_t)K * 8);
    int*    perm    = (int*)take((size_t)K * 4);
    double* yrv     = (double*)take((size_t)N * 8);
    double* ynv     = (double*)take((size_t)N * 8);
    (void)ws_size;

    hipMemsetAsync(counts, 0, (size_t)N * 4, stream);
    hipMemsetAsync(rankcnt, 0, (size_t)N * 4, stream);

    count_kernel<<<(E + 255) / 256, 256, 0, stream>>>(dst, counts, E);
    scan_kernel<<<1, 1024, 0, stream>>>(counts, offs, N, E);
    fill_kernel<<<(E + 255) / 256, 256, 0, stream>>>(dst, offs, counts, csr, E);
    bsort_kernel<<<(N + 255) / 256, 256, 0, stream>>>(csr, offs, src, N);

    // layer 0: virtual-concat inputs (no materialized x0), BK=64
    segsum_first_kernel<<<N / 4, 256, 0, stream>>>(f0, f1, csr, offs, agg, N);
    gemm_first_k64_kernel<<<dim3(256 / GBN, N / GBM), 256, 0, stream>>>(
        f0, f1, agg, Wr, Wn, b, xB);

    // layer 1: BK=64
    segsum_kernel<<<N / 4, 256, 0, stream>>>(xB, csr, offs, agg, N);
    gemm_two_k64_kernel<<<dim3(256 / GBN, N / GBM), 256, 0, stream>>>(
        xB, agg, Wr + 65536, Wn + 65536, b + 256, xA);

    // layer 2: BK=64
    segsum_kernel<<<N / 4, 256, 0, stream>>>(xA, csr, offs, agg, N);
    gemm_two_k64_kernel<<<dim3(256 / GBN, N / GBM), 256, 0, stream>>>(
        xA, agg, Wr + 2 * 65536, Wn + 2 * 65536, b + 2 * 256, xB);

    float* xcur = xB;  // x3
    dot_kernel<<<N / 4, 256, 0, stream>>>(xcur, Wpr, Wpn, yrv, ynv, N);
    score_gather_kernel<<<N / 256, 256, 0, stream>>>(yrv, ynv, csr, offs, bp, sc, keys, N);
    rank_count_kernel<<<dim3(N / RTJ, N / RTI), 256, 0, stream>>>(keys, rankcnt, N);
    rank_scatter_kernel<<<(N + 255) / 256, 256, 0, stream>>>(rankcnt, sc, perm, topd, N, K);
    out_kernel<<<K / 4, 256, 0, stream>>>(xcur, perm, topd, Wc, bc, out, K);
}